// Round 8
// baseline (833.519 us; speedup 1.0000x reference)
//
#include <hip/hip_runtime.h>
#include <stdint.h>

#define HIDD 128
#define NNODES 100000
#define NEDGES 800000
#define NSEG 196          // ceil(100000/512) segments for the scan

typedef short s16x8 __attribute__((ext_vector_type(8)));
typedef float f32x4 __attribute__((ext_vector_type(4)));

__device__ __forceinline__ short f2bf(float f) {
  union { float f; unsigned u; } v; v.f = f;
  return (short)((v.u + 0x7fffu + ((v.u >> 16) & 1u)) >> 16);
}
__device__ __forceinline__ short4 cvt4(float4 v) {
  short4 s; s.x = f2bf(v.x); s.y = f2bf(v.y); s.z = f2bf(v.z); s.w = f2bf(v.w);
  return s;
}
__device__ __forceinline__ float bflo(unsigned w) {
  union { unsigned u; float f; } v; v.u = w << 16; return v.f;
}
__device__ __forceinline__ float bfhi(unsigned w) {
  union { unsigned u; float f; } v; v.u = w & 0xffff0000u; return v.f;
}
__device__ __forceinline__ unsigned pack2(float a, float b) {
  return ((unsigned)(unsigned short)f2bf(b) << 16) | (unsigned)(unsigned short)f2bf(a);
}
__device__ __forceinline__ f32x4 mfma16(s16x8 a, s16x8 b, f32x4 c) {
  return __builtin_amdgcn_mfma_f32_16x16x32_bf16(a, b, c, 0, 0, 0);
}
__device__ __forceinline__ void atomic_pk_bf16(unsigned short* addr, unsigned pk) {
  asm volatile("global_atomic_pk_add_bf16 %0, %1, off" :: "v"(addr), "v"(pk) : "memory");
}

// ---------- prep: h -> bf16 ----------
__global__ void k_prep_h(const float4* __restrict__ h4, short4* __restrict__ hb4, int n4) {
  int stride = gridDim.x * blockDim.x;
  for (int i = blockIdx.x * blockDim.x + threadIdx.x; i < n4; i += stride)
    hb4[i] = cvt4(h4[i]);
}

// ---------- prep: weights -> bf16 [out][in]; w2e col-permuted ----------
__global__ void k_prep_w(const float* __restrict__ w1e, const float* __restrict__ w2e,
                         const float* __restrict__ w1u, const float* __restrict__ w2u,
                         short* __restrict__ w1et, short* __restrict__ w2et,
                         short* __restrict__ w1ut, short* __restrict__ w2ut) {
  int i = blockIdx.x * 256 + threadIdx.x;
  if (i < 49152) {               // dest [128][384]: n=i/384, k=i%384
    int n = i / 384, k = i - n * 384;
    w1et[i] = f2bf(w1e[k * 128 + n]);
    w1ut[i] = f2bf(w1u[k * 128 + n]);
  } else {
    int j = i - 49152;
    if (j < 16384) {             // dest [128][128]: n=j>>7, k=j&127
      int n = j >> 7, k = j & 127;
      int oc = (n & ~31) + 2 * (n & 15) + ((n >> 4) & 1);
      w2et[j] = f2bf(w2e[k * 128 + oc]);   // permuted
      w2ut[j] = f2bf(w2u[k * 128 + n]);    // natural
    }
  }
}

// ================= counting-sort chain =================
__global__ void k_hist(const int* __restrict__ eidx, int* __restrict__ cnt_s,
                       int* __restrict__ cnt_d) {
  int i = blockIdx.x * 256 + threadIdx.x;
  if (i < NEDGES) {
    atomicAdd(&cnt_s[eidx[i]], 1);
    atomicAdd(&cnt_d[eidx[NEDGES + i]], 1);
  }
}

__global__ void k_bsum(const int* __restrict__ cnt_d, const int* __restrict__ cnt_s,
                       int* __restrict__ bsum) {
  __shared__ int red[256];
  int gb = blockIdx.x, sel = gb >= NSEG, b = gb - sel * NSEG;
  const int* cnt = sel ? cnt_s : cnt_d;
  int t = threadIdx.x;
  int i0 = b * 512 + 2 * t;
  int a = (i0 < NNODES) ? cnt[i0] : 0;
  int c = (i0 + 1 < NNODES) ? cnt[i0 + 1] : 0;
  red[t] = a + c;
  __syncthreads();
  for (int d = 128; d > 0; d >>= 1) {
    if (t < d) red[t] += red[t + d];
    __syncthreads();
  }
  if (t == 0) bsum[gb] = red[0];
}

__global__ void k_soff(int* __restrict__ bsum, int* __restrict__ off_d,
                       int* __restrict__ off_s) {
  if (threadIdx.x == 0) {
    int tot = 0;
    for (int i = 0; i < NSEG; ++i) { int v = bsum[i]; bsum[i] = tot; tot += v; }
    off_d[NNODES] = tot;
  } else if (threadIdx.x == 1) {
    int tot = 0;
    for (int i = NSEG; i < 2 * NSEG; ++i) { int v = bsum[i]; bsum[i] = tot; tot += v; }
    off_s[NNODES] = tot;
  }
}

__global__ void k_sfin(const int* __restrict__ cnt_d, const int* __restrict__ cnt_s,
                       const int* __restrict__ bsum,
                       int* __restrict__ off_d, int* __restrict__ off_s,
                       int* __restrict__ cur_d, int* __restrict__ cur_s) {
  __shared__ int p[256];
  int gb = blockIdx.x, sel = gb >= NSEG, b = gb - sel * NSEG;
  const int* cnt = sel ? cnt_s : cnt_d;
  int* off = sel ? off_s : off_d;
  int* cur = sel ? cur_s : cur_d;
  int t = threadIdx.x;
  int i0 = b * 512 + 2 * t;
  int a = (i0 < NNODES) ? cnt[i0] : 0;
  int c = (i0 + 1 < NNODES) ? cnt[i0 + 1] : 0;
  p[t] = a + c;
  __syncthreads();
  for (int d = 1; d < 256; d <<= 1) {
    int v = (t >= d) ? p[t - d] : 0;
    __syncthreads();
    p[t] += v;
    __syncthreads();
  }
  int excl = (t ? p[t - 1] : 0) + bsum[gb];
  if (i0 < NNODES)     { off[i0] = excl;     cur[i0] = excl; }
  if (i0 + 1 < NNODES) { off[i0 + 1] = excl + a; cur[i0 + 1] = excl + a; }
}

// emit per-edge CSR slot
__global__ void k_scat2(const int* __restrict__ eidx, int* __restrict__ cur_s,
                        int* __restrict__ cur_d, int* __restrict__ slot_s,
                        int* __restrict__ slot_d) {
  int i = blockIdx.x * 256 + threadIdx.x;
  if (i < NEDGES) {
    slot_s[i] = atomicAdd(&cur_s[eidx[i]], 1);
    slot_d[i] = atomicAdd(&cur_d[eidx[NEDGES + i]], 1);
  }
}

// ================= edge MLP -> messages in CSR order; 3 blocks/CU =================
__global__ __launch_bounds__(256, 3)
void k_edge2(const short* __restrict__ hb, const int* __restrict__ eidx,
             const float* __restrict__ ex,
             const short* __restrict__ w1t, const short* __restrict__ w2t,
             const float* __restrict__ b1g, const float* __restrict__ b2g,
             const int* __restrict__ slot_s, const int* __restrict__ slot_d,
             unsigned* __restrict__ msg_s, unsigned* __restrict__ msg_d) {
  __shared__ __align__(16) char smem[51200];
  short (*Xh)[264] = (short (*)[264])smem;            // h[src]|h[dst], 33792 B
  short (*Xe)[136] = (short (*)[136])(smem + 33792);  // edge_x, 17408 B
  short (*Hs)[136] = (short (*)[136])(smem + 33792);  // hidden, ALIASES Xe

  const int tid = threadIdx.x;
  const int wave = tid >> 6, lane = tid & 63;
  const int lg = lane >> 4, lr = lane & 15;
  const int koff = lg * 8;
  const int c0 = wave * 32 + lr, c1 = c0 + 16;
  const int pc0 = wave * 32 + 2 * lr;   // natural col of frag0 (permuted W2)

  s16x8 wb1a[12], wb1b[12], wb2a[4], wb2b[4];
#pragma unroll
  for (int kk = 0; kk < 12; ++kk) {
    wb1a[kk] = *(const s16x8*)(w1t + c0 * 384 + kk * 32 + koff);
    wb1b[kk] = *(const s16x8*)(w1t + c1 * 384 + kk * 32 + koff);
  }
#pragma unroll
  for (int kk = 0; kk < 4; ++kk) {
    wb2a[kk] = *(const s16x8*)(w2t + c0 * 128 + kk * 32 + koff);
    wb2b[kk] = *(const s16x8*)(w2t + c1 * 128 + kk * 32 + koff);
  }
  const float bias1_0 = b1g[c0], bias1_1 = b1g[c1];
  const float bias2_0 = b2g[pc0], bias2_1 = b2g[pc0 + 1];

  for (int t = blockIdx.x; t < NEDGES / 64; t += gridDim.x) {
    const int base = t * 64;

    // Phase A: stage h and edge_x through LDS once per block (R4/R5 lesson);
    // slots go to per-lane REGISTERS (no LDS, no store-protecting barrier).
    for (int u = tid; u < 64 * 32; u += 256) {
      int r = u >> 5, c = u & 31;
      int node = (c < 16) ? eidx[base + r] : eidx[NEDGES + base + r];
      *(int4*)&Xh[r][c * 8] = *(const int4*)(hb + (long)node * 128 + (c & 15) * 8);
    }
    for (int u = tid; u < 64 * 32; u += 256) {
      int r = u >> 5, q = u & 31;
      float4 v = *(const float4*)(ex + (long)(base + r) * 128 + q * 4);
      *(short4*)&Xe[r][q * 4] = cvt4(v);
    }
    int ssl[16], sdl[16];
#pragma unroll
    for (int m = 0; m < 4; ++m)
#pragma unroll
      for (int r2 = 0; r2 < 4; ++r2) {
        int row = m * 16 + lg * 4 + r2;
        ssl[m * 4 + r2] = slot_s[base + row];
        sdl[m * 4 + r2] = slot_d[base + row];
      }
    __syncthreads();   // bar1: staging visible (also drains prev tile's stores)

    // Phase B: layer 1 (Xh: K 0..255, Xe: K 256..383)
    f32x4 acc[4][2] = {};
#pragma unroll
    for (int kk = 0; kk < 8; ++kk) {
      int k0 = kk * 32 + koff;
#pragma unroll
      for (int m = 0; m < 4; ++m) {
        s16x8 a = *(const s16x8*)&Xh[m * 16 + lr][k0];
        acc[m][0] = mfma16(a, wb1a[kk], acc[m][0]);
        acc[m][1] = mfma16(a, wb1b[kk], acc[m][1]);
      }
    }
#pragma unroll
    for (int kk = 0; kk < 4; ++kk) {
      int k0 = kk * 32 + koff;
#pragma unroll
      for (int m = 0; m < 4; ++m) {
        s16x8 a = *(const s16x8*)&Xe[m * 16 + lr][k0];
        acc[m][0] = mfma16(a, wb1a[8 + kk], acc[m][0]);
        acc[m][1] = mfma16(a, wb1b[8 + kk], acc[m][1]);
      }
    }
    __syncthreads();   // bar2: all waves done reading Xe (Hs will alias it)

#pragma unroll
    for (int m = 0; m < 4; ++m)
#pragma unroll
      for (int r2 = 0; r2 < 4; ++r2) {
        int row = m * 16 + lg * 4 + r2;
        Hs[row][c0] = f2bf(fmaxf(acc[m][0][r2] + bias1_0, 0.f));
        Hs[row][c1] = f2bf(fmaxf(acc[m][1][r2] + bias1_1, 0.f));
      }
    __syncthreads();   // bar3: Hs ready

    // Phase C: layer 2
    f32x4 acc2[4][2] = {};
#pragma unroll
    for (int kk = 0; kk < 4; ++kk) {
      int k0 = kk * 32 + koff;
#pragma unroll
      for (int m = 0; m < 4; ++m) {
        s16x8 a = *(const s16x8*)&Hs[m * 16 + lr][k0];
        acc2[m][0] = mfma16(a, wb2a[kk], acc2[m][0]);
        acc2[m][1] = mfma16(a, wb2b[kk], acc2[m][1]);
      }
    }
    __syncthreads();   // bar4: Hs reads retired; next stage may overwrite LDS

    // dual CSR-ordered store — fire-and-forget, drains at NEXT tile's bar1
#pragma unroll
    for (int m = 0; m < 4; ++m)
#pragma unroll
      for (int r2 = 0; r2 < 4; ++r2) {
        unsigned pk = pack2(acc2[m][0][r2] + bias2_0, acc2[m][1][r2] + bias2_1);
        int lo = wave * 16 + lr;
        msg_s[(long)ssl[m * 4 + r2] * 64 + lo] = pk;
        msg_d[(long)sdl[m * 4 + r2] * 64 + lo] = pk;
      }
  }
}

// ================= node: streaming CSR aggregate + MLP + LN; 3 blocks/CU =================
__global__ __launch_bounds__(256, 3)
void k_node2(const float* __restrict__ h, const short* __restrict__ hb,
             const unsigned* __restrict__ msg_d, const int* __restrict__ off_d,
             const unsigned* __restrict__ msg_s, const int* __restrict__ off_s,
             const short* __restrict__ w1t, const short* __restrict__ w2t,
             const float* __restrict__ b1g, const float* __restrict__ b2g,
             const float* __restrict__ lng, const float* __restrict__ lnb,
             float* __restrict__ out) {
  __shared__ __align__(16) char smem[50688];
  short (*Xs)[396] = (short (*)[396])smem;            // 50688 B (pad 12)
  short (*Hs)[132] = (short (*)[132])smem;            // 16896 B, aliases Xs
  float (*Xf)[132] = (float (*)[132])(smem + 16896);  // 33792 B, aliases Xs

  const int tid = threadIdx.x;
  const int wave = tid >> 6, lane = tid & 63;
  const int lg = lane >> 4, lr = lane & 15;
  const int koff = lg * 8;
  const int c0 = wave * 32 + lr, c1 = c0 + 16;

  s16x8 wb1a[12], wb1b[12], wb2a[4], wb2b[4];
#pragma unroll
  for (int kk = 0; kk < 12; ++kk) {
    wb1a[kk] = *(const s16x8*)(w1t + c0 * 384 + kk * 32 + koff);
    wb1b[kk] = *(const s16x8*)(w1t + c1 * 384 + kk * 32 + koff);
  }
#pragma unroll
  for (int kk = 0; kk < 4; ++kk) {
    wb2a[kk] = *(const s16x8*)(w2t + c0 * 128 + kk * 32 + koff);
    wb2b[kk] = *(const s16x8*)(w2t + c1 * 128 + kk * 32 + koff);
  }
  const float bias1_0 = b1g[c0], bias1_1 = b1g[c1];
  const float bias2_0 = b2g[c0], bias2_1 = b2g[c1];

  const int ntiles = (NNODES + 63) / 64;
  for (int t = blockIdx.x; t < ntiles; t += gridDim.x) {
    const int base = t * 64;

    // Phase A: h copy + streaming aggregation into Xs
    for (int u = tid; u < 64 * 16; u += 256) {
      int r = u >> 4, c = u & 15;
      long node = min(base + r, NNODES - 1);
      *(int4*)&Xs[r][c * 8] = *(const int4*)(hb + node * 128 + c * 8);
    }
    {
      int r = tid >> 2, q = tid & 3;
      long node = base + r;
      bool valid = node < NNODES;
#pragma unroll
      for (int dir = 0; dir < 2; ++dir) {
        const int* off = dir ? off_s : off_d;
        const unsigned* msg = dir ? msg_s : msg_d;
        float av[32];
#pragma unroll
        for (int j = 0; j < 32; ++j) av[j] = 0.f;
        int e0 = 0, e1 = 0;
        if (valid) { e0 = off[node]; e1 = off[node + 1]; }
        for (int e = e0; e < e1; ++e) {
          const uint4* mp = (const uint4*)(msg + (long)e * 64 + q * 16);
          uint4 u0 = mp[0], u1 = mp[1], u2 = mp[2], u3 = mp[3];
          av[0]  += bflo(u0.x); av[1]  += bfhi(u0.x);
          av[2]  += bflo(u0.y); av[3]  += bfhi(u0.y);
          av[4]  += bflo(u0.z); av[5]  += bfhi(u0.z);
          av[6]  += bflo(u0.w); av[7]  += bfhi(u0.w);
          av[8]  += bflo(u1.x); av[9]  += bfhi(u1.x);
          av[10] += bflo(u1.y); av[11] += bfhi(u1.y);
          av[12] += bflo(u1.z); av[13] += bfhi(u1.z);
          av[14] += bflo(u1.w); av[15] += bfhi(u1.w);
          av[16] += bflo(u2.x); av[17] += bfhi(u2.x);
          av[18] += bflo(u2.y); av[19] += bfhi(u2.y);
          av[20] += bflo(u2.z); av[21] += bfhi(u2.z);
          av[22] += bflo(u2.w); av[23] += bfhi(u2.w);
          av[24] += bflo(u3.x); av[25] += bfhi(u3.x);
          av[26] += bflo(u3.y); av[27] += bfhi(u3.y);
          av[28] += bflo(u3.z); av[29] += bfhi(u3.z);
          av[30] += bflo(u3.w); av[31] += bfhi(u3.w);
        }
        float sc = 1.f / fmaxf((float)(e1 - e0), 1.f);
        unsigned pk[16];
#pragma unroll
        for (int j = 0; j < 16; ++j) pk[j] = pack2(av[2 * j] * sc, av[2 * j + 1] * sc);
        uint4* dst = (uint4*)&Xs[r][(dir ? 256 : 128) + q * 32];
        dst[0] = make_uint4(pk[0], pk[1], pk[2], pk[3]);
        dst[1] = make_uint4(pk[4], pk[5], pk[6], pk[7]);
        dst[2] = make_uint4(pk[8], pk[9], pk[10], pk[11]);
        dst[3] = make_uint4(pk[12], pk[13], pk[14], pk[15]);
      }
    }
    __syncthreads();   // bar1

    // Phase B: layer 1
    f32x4 acc[4][2] = {};
#pragma unroll
    for (int kk = 0; kk < 12; ++kk) {
      int k0 = kk * 32 + koff;
#pragma unroll
      for (int m = 0; m < 4; ++m) {
        s16x8 a = *(const s16x8*)&Xs[m * 16 + lr][k0];
        acc[m][0] = mfma16(a, wb1a[kk], acc[m][0]);
        acc[m][1] = mfma16(a, wb1b[kk], acc[m][1]);
      }
    }
    __syncthreads();   // bar2: Xs reads retired (Hs/Xf alias it)

#pragma unroll
    for (int m = 0; m < 4; ++m)
#pragma unroll
      for (int r2 = 0; r2 < 4; ++r2) {
        int row = m * 16 + lg * 4 + r2;
        Hs[row][c0] = f2bf(fmaxf(acc[m][0][r2] + bias1_0, 0.f));
        Hs[row][c1] = f2bf(fmaxf(acc[m][1][r2] + bias1_1, 0.f));
      }
    __syncthreads();   // bar3: Hs ready

    // Phase C: layer 2 + residual -> Xf
    f32x4 acc2[4][2] = {};
#pragma unroll
    for (int kk = 0; kk < 4; ++kk) {
      int k0 = kk * 32 + koff;
#pragma unroll
      for (int m = 0; m < 4; ++m) {
        s16x8 a = *(const s16x8*)&Hs[m * 16 + lr][k0];
        acc2[m][0] = mfma16(a, wb2a[kk], acc2[m][0]);
        acc2[m][1] = mfma16(a, wb2b[kk], acc2[m][1]);
      }
    }
#pragma unroll
    for (int m = 0; m < 4; ++m)
#pragma unroll
      for (int r2 = 0; r2 < 4; ++r2) {
        int row = m * 16 + lg * 4 + r2;
        long node = base + row;
        float h0 = 0.f, h1 = 0.f;
        if (node < NNODES) { h0 = h[node * 128 + c0]; h1 = h[node * 128 + c1]; }
        Xf[row][c0] = acc2[m][0][r2] + bias2_0 + h0;   // disjoint from Hs region
        Xf[row][c1] = acc2[m][1][r2] + bias2_1 + h1;
      }
    __syncthreads();   // bar4: Xf ready

    // Phase D: LayerNorm + store
    {
      int r = tid >> 2, q = tid & 3;
      float sum = 0.f, ss = 0.f;
      float4 vals[8];
#pragma unroll
      for (int j = 0; j < 8; ++j) {
        float4 v = *(const float4*)&Xf[r][q * 32 + j * 4];
        vals[j] = v;
        sum += v.x + v.y + v.z + v.w;
        ss += v.x * v.x + v.y * v.y + v.z * v.z + v.w * v.w;
      }
      sum += __shfl_xor(sum, 1); sum += __shfl_xor(sum, 2);
      ss  += __shfl_xor(ss, 1);  ss  += __shfl_xor(ss, 2);
      float mean = sum * (1.f / 128.f);
      float var = ss * (1.f / 128.f) - mean * mean;
      float rstd = rsqrtf(var + 1e-5f);
      long node = base + r;
      if (node < NNODES) {
#pragma unroll
        for (int j = 0; j < 8; ++j) {
          int cc = q * 32 + j * 4;
          float4 v = vals[j];
          float4 o;
          o.x = (v.x - mean) * rstd * lng[cc + 0] + lnb[cc + 0];
          o.y = (v.y - mean) * rstd * lng[cc + 1] + lnb[cc + 1];
          o.z = (v.z - mean) * rstd * lng[cc + 2] + lnb[cc + 2];
          o.w = (v.w - mean) * rstd * lng[cc + 3] + lnb[cc + 3];
          *(float4*)(out + node * 128 + cc) = o;
        }
      }
    }
    __syncthreads();   // bar5: Xf reads done before next tile's staging
  }
}

// ================= fallback path (R3, proven): pk-bf16 atomics =================
__global__ __launch_bounds__(256, 2)
void k_edge_at(const short* __restrict__ hb, const int* __restrict__ eidx,
               const float* __restrict__ ex,
               const short* __restrict__ w1t, const short* __restrict__ w2t,
               const float* __restrict__ b1g, const float* __restrict__ b2g,
               unsigned short* __restrict__ incb, unsigned short* __restrict__ outgb,
               float* __restrict__ indeg, float* __restrict__ outdeg) {
  __shared__ __align__(16) short Xs[64][392];
  __shared__ __align__(16) short Hs[64][136];
  const int tid = threadIdx.x;
  const int wave = tid >> 6, lane = tid & 63;
  const int lg = lane >> 4, lr = lane & 15;
  const int koff = lg * 8;
  const int c0 = wave * 32 + lr, c1 = c0 + 16;
  const int pc0 = wave * 32 + 2 * lr;
  s16x8 wb1a[12], wb1b[12], wb2a[4], wb2b[4];
#pragma unroll
  for (int kk = 0; kk < 12; ++kk) {
    wb1a[kk] = *(const s16x8*)(w1t + c0 * 384 + kk * 32 + koff);
    wb1b[kk] = *(const s16x8*)(w1t + c1 * 384 + kk * 32 + koff);
  }
#pragma unroll
  for (int kk = 0; kk < 4; ++kk) {
    wb2a[kk] = *(const s16x8*)(w2t + c0 * 128 + kk * 32 + koff);
    wb2b[kk] = *(const s16x8*)(w2t + c1 * 128 + kk * 32 + koff);
  }
  const float bias1_0 = b1g[c0], bias1_1 = b1g[c1];
  const float bias2_0 = b2g[pc0], bias2_1 = b2g[pc0 + 1];
  for (int t = blockIdx.x; t < NEDGES / 64; t += gridDim.x) {
    const int base = t * 64;
    for (int u = tid; u < 64 * 32; u += 256) {
      int r = u >> 5, c = u & 31;
      int node = (c < 16) ? eidx[base + r] : eidx[NEDGES + base + r];
      *(int4*)&Xs[r][c * 8] = *(const int4*)(hb + (long)node * 128 + (c & 15) * 8);
    }
    for (int u = tid; u < 64 * 32; u += 256) {
      int r = u >> 5, q = u & 31;
      float4 v = *(const float4*)(ex + (long)(base + r) * 128 + q * 4);
      *(short4*)&Xs[r][256 + q * 4] = cvt4(v);
    }
    if (tid < 64) {
      atomicAdd(&outdeg[eidx[base + tid]], 1.0f);
      atomicAdd(&indeg[eidx[NEDGES + base + tid]], 1.0f);
    }
    __syncthreads();
    f32x4 acc[4][2] = {};
#pragma unroll
    for (int kk = 0; kk < 12; ++kk) {
      int k0 = kk * 32 + koff;
#pragma unroll
      for (int m = 0; m < 4; ++m) {
        s16x8 a = *(const s16x8*)&Xs[m * 16 + lr][k0];
        acc[m][0] = mfma16(a, wb1a[kk], acc[m][0]);
        acc[m][1] = mfma16(a, wb1b[kk], acc[m][1]);
      }
    }
#pragma unroll
    for (int m = 0; m < 4; ++m)
#pragma unroll
      for (int r2 = 0; r2 < 4; ++r2) {
        int row = m * 16 + lg * 4 + r2;
        Hs[row][c0] = f2bf(fmaxf(acc[m][0][r2] + bias1_0, 0.f));
        Hs[row][c1] = f2bf(fmaxf(acc[m][1][r2] + bias1_1, 0.f));
      }
    __syncthreads();
    f32x4 acc2[4][2] = {};
#pragma unroll
    for (int kk = 0; kk < 4; ++kk) {
#pragma unroll
      for (int m = 0; m < 4; ++m) {
        s16x8 a = *(const s16x8*)&Hs[m * 16 + lr][kk * 32 + koff];
        acc2[m][0] = mfma16(a, wb2a[kk], acc2[m][0]);
        acc2[m][1] = mfma16(a, wb2b[kk], acc2[m][1]);
      }
    }
#pragma unroll
    for (int m = 0; m < 4; ++m)
#pragma unroll
      for (int r2 = 0; r2 < 4; ++r2) {
        int row = m * 16 + lg * 4 + r2;
        int s = eidx[base + row], d = eidx[NEDGES + base + row];
        unsigned pk = pack2(acc2[m][0][r2] + bias2_0, acc2[m][1][r2] + bias2_1);
        atomic_pk_bf16(outgb + (long)s * 128 + pc0, pk);
        atomic_pk_bf16(incb + (long)d * 128 + pc0, pk);
      }
  }
}

__global__ __launch_bounds__(256, 2)
void k_node_at(const float* __restrict__ h, const short* __restrict__ hb,
               const unsigned short* __restrict__ incb,
               const unsigned short* __restrict__ outgb,
               const float* __restrict__ indeg, const float* __restrict__ outdeg,
               const short* __restrict__ w1t, const short* __restrict__ w2t,
               const float* __restrict__ b1g, const float* __restrict__ b2g,
               const float* __restrict__ lng, const float* __restrict__ lnb,
               float* __restrict__ out) {
  __shared__ __align__(16) char smem[67584];
  short (*Xs)[392] = (short (*)[392])smem;
  float (*Xf)[132] = (float (*)[132])smem;
  short (*Hs)[136] = (short (*)[136])(smem + 50176);
  const int tid = threadIdx.x;
  const int wave = tid >> 6, lane = tid & 63;
  const int lg = lane >> 4, lr = lane & 15;
  const int koff = lg * 8;
  const int c0 = wave * 32 + lr, c1 = c0 + 16;
  s16x8 wb1a[12], wb1b[12], wb2a[4], wb2b[4];
#pragma unroll
  for (int kk = 0; kk < 12; ++kk) {
    wb1a[kk] = *(const s16x8*)(w1t + c0 * 384 + kk * 32 + koff);
    wb1b[kk] = *(const s16x8*)(w1t + c1 * 384 + kk * 32 + koff);
  }
#pragma unroll
  for (int kk = 0; kk < 4; ++kk) {
    wb2a[kk] = *(const s16x8*)(w2t + c0 * 128 + kk * 32 + koff);
    wb2b[kk] = *(const s16x8*)(w2t + c1 * 128 + kk * 32 + koff);
  }
  const float bias1_0 = b1g[c0], bias1_1 = b1g[c1];
  const float bias2_0 = b2g[c0], bias2_1 = b2g[c1];
  const int ntiles = (NNODES + 63) / 64;
  for (int t = blockIdx.x; t < ntiles; t += gridDim.x) {
    const int base = t * 64;
    for (int u = tid; u < 64 * 16; u += 256) {
      int r = u >> 4, c = u & 15;
      long node = min(base + r, NNODES - 1);
      *(int4*)&Xs[r][c * 8] = *(const int4*)(hb + node * 128 + c * 8);
    }
    for (int u = tid; u < 64 * 16; u += 256) {
      int r = u >> 4, c = u & 15;
      long node = min(base + r, NNODES - 1);
      float s = 1.f / fmaxf(indeg[node], 1.f);
      uint4 w = *(const uint4*)(incb + node * 128 + c * 8);
      *(uint4*)&Xs[r][128 + c * 8] = make_uint4(
        pack2(bflo(w.x) * s, bfhi(w.x) * s), pack2(bflo(w.y) * s, bfhi(w.y) * s),
        pack2(bflo(w.z) * s, bfhi(w.z) * s), pack2(bflo(w.w) * s, bfhi(w.w) * s));
    }
    for (int u = tid; u < 64 * 16; u += 256) {
      int r = u >> 4, c = u & 15;
      long node = min(base + r, NNODES - 1);
      float s = 1.f / fmaxf(outdeg[node], 1.f);
      uint4 w = *(const uint4*)(outgb + node * 128 + c * 8);
      *(uint4*)&Xs[r][256 + c * 8] = make_uint4(
        pack2(bflo(w.x) * s, bfhi(w.x) * s), pack2(bflo(w.y) * s, bfhi(w.y) * s),
        pack2(bflo(w.z) * s, bfhi(w.z) * s), pack2(bflo(w.w) * s, bfhi(w.w) * s));
    }
    __syncthreads();
    f32x4 acc[4][2] = {};
#pragma unroll
    for (int kk = 0; kk < 12; ++kk) {
      int k0 = kk * 32 + koff;
#pragma unroll
      for (int m = 0; m < 4; ++m) {
        s16x8 a = *(const s16x8*)&Xs[m * 16 + lr][k0];
        acc[m][0] = mfma16(a, wb1a[kk], acc[m][0]);
        acc[m][1] = mfma16(a, wb1b[kk], acc[m][1]);
      }
    }
#pragma unroll
    for (int m = 0; m < 4; ++m)
#pragma unroll
      for (int r2 = 0; r2 < 4; ++r2) {
        int row = m * 16 + lg * 4 + r2;
        Hs[row][c0] = f2bf(fmaxf(acc[m][0][r2] + bias1_0, 0.f));
        Hs[row][c1] = f2bf(fmaxf(acc[m][1][r2] + bias1_1, 0.f));
      }
    __syncthreads();
    f32x4 acc2[4][2] = {};
#pragma unroll
    for (int kk = 0; kk < 4; ++kk) {
      int k0 = kk * 32 + koff;
#pragma unroll
      for (int m = 0; m < 4; ++m) {
        s16x8 a = *(const s16x8*)&Hs[m * 16 + lr][k0];
        acc2[m][0] = mfma16(a, wb2a[kk], acc2[m][0]);
        acc2[m][1] = mfma16(a, wb2b[kk], acc2[m][1]);
      }
    }
#pragma unroll
    for (int m = 0; m < 4; ++m)
#pragma unroll
      for (int r2 = 0; r2 < 4; ++r2) {
        int row = m * 16 + lg * 4 + r2;
        long node = base + row;
        float h0 = 0.f, h1 = 0.f;
        if (node < NNODES) { h0 = h[node * 128 + c0]; h1 = h[node * 128 + c1]; }
        Xf[row][c0] = acc2[m][0][r2] + bias2_0 + h0;
        Xf[row][c1] = acc2[m][1][r2] + bias2_1 + h1;
      }
    __syncthreads();
    {
      int r = tid >> 2, q = tid & 3;
      float sum = 0.f, ss = 0.f;
      float4 vals[8];
#pragma unroll
      for (int j = 0; j < 8; ++j) {
        float4 v = *(const float4*)&Xf[r][q * 32 + j * 4];
        vals[j] = v;
        sum += v.x + v.y + v.z + v.w;
        ss += v.x * v.x + v.y * v.y + v.z * v.z + v.w * v.w;
      }
      sum += __shfl_xor(sum, 1); sum += __shfl_xor(sum, 2);
      ss  += __shfl_xor(ss, 1);  ss  += __shfl_xor(ss, 2);
      float mean = sum * (1.f / 128.f);
      float var = ss * (1.f / 128.f) - mean * mean;
      float rstd = rsqrtf(var + 1e-5f);
      long node = base + r;
      if (node < NNODES) {
#pragma unroll
        for (int j = 0; j < 8; ++j) {
          int cc = q * 32 + j * 4;
          float4 v = vals[j];
          float4 o;
          o.x = (v.x - mean) * rstd * lng[cc + 0] + lnb[cc + 0];
          o.y = (v.y - mean) * rstd * lng[cc + 1] + lnb[cc + 1];
          o.z = (v.z - mean) * rstd * lng[cc + 2] + lnb[cc + 2];
          o.w = (v.w - mean) * rstd * lng[cc + 3] + lnb[cc + 3];
          *(float4*)(out + node * 128 + cc) = o;
        }
      }
    }
    __syncthreads();
  }
}

extern "C" void kernel_launch(void* const* d_in, const int* in_sizes, int n_in,
                              void* d_out, int out_size, void* d_ws, size_t ws_size,
                              hipStream_t stream) {
  const float* h    = (const float*)d_in[0];
  const int*   ei   = (const int*)d_in[1];
  const float* ex   = (const float*)d_in[2];
  const float* epw1 = (const float*)d_in[3];
  const float* epb1 = (const float*)d_in[4];
  const float* epw2 = (const float*)d_in[5];
  const float* epb2 = (const float*)d_in[6];
  const float* upw1 = (const float*)d_in[7];
  const float* upb1 = (const float*)d_in[8];
  const float* upw2 = (const float*)d_in[9];
  const float* upb2 = (const float*)d_in[10];
  const float* lng  = (const float*)d_in[11];
  const float* lnb  = (const float*)d_in[12];
  float* out = (float*)d_out;
  char* ws = (char*)d_ws;

  const size_t NEED = 444300000ULL;
  if (ws_size >= NEED) {
    unsigned* msg_s = (unsigned*)(ws);                      // 204,800,000
    unsigned* msg_d = (unsigned*)(ws + 204800000);          // 204,800,000
    short* hb    = (short*)(ws + 409600000);                //  25,600,000
    short* w1et  = (short*)(ws + 435200000);
    short* w2et  = (short*)(ws + 435298304);
    short* w1ut  = (short*)(ws + 435331072);
    short* w2ut  = (short*)(ws + 435429376);
    int* cnt_d   = (int*)(ws + 435462144);
    int* cnt_s   = (int*)(ws + 435862144);
    int* off_d   = (int*)(ws + 436262144);
    int* off_s   = (int*)(ws + 436662148);
    int* cur_d   = (int*)(ws + 437062152);
    int* cur_s   = (int*)(ws + 437462152);
    int* slot_s  = (int*)(ws + 437862152);
    int* slot_d  = (int*)(ws + 441062152);
    int* bsum    = (int*)(ws + 444262152);

    hipMemsetAsync(cnt_d, 0, 800000, stream);               // cnt_d + cnt_s
    hipLaunchKernelGGL(k_prep_h, dim3(2048), dim3(256), 0, stream,
                       (const float4*)h, (short4*)hb, NNODES * 128 / 4);
    hipLaunchKernelGGL(k_prep_w, dim3(256), dim3(256), 0, stream,
                       epw1, epw2, upw1, upw2, w1et, w2et, w1ut, w2ut);
    hipLaunchKernelGGL(k_hist, dim3((NEDGES + 255) / 256), dim3(256), 0, stream,
                       ei, cnt_s, cnt_d);
    hipLaunchKernelGGL(k_bsum, dim3(2 * NSEG), dim3(256), 0, stream,
                       cnt_d, cnt_s, bsum);
    hipLaunchKernelGGL(k_soff, dim3(1), dim3(64), 0, stream, bsum, off_d, off_s);
    hipLaunchKernelGGL(k_sfin, dim3(2 * NSEG), dim3(256), 0, stream,
                       cnt_d, cnt_s, bsum, off_d, off_s, cur_d, cur_s);
    hipLaunchKernelGGL(k_scat2, dim3((NEDGES + 255) / 256), dim3(256), 0, stream,
                       ei, cur_s, cur_d, slot_s, slot_d);
    hipLaunchKernelGGL(k_edge2, dim3(768), dim3(256), 0, stream,
                       hb, ei, ex, w1et, w2et, epb1, epb2, slot_s, slot_d,
                       msg_s, msg_d);
    hipLaunchKernelGGL(k_node2, dim3(768), dim3(256), 0, stream,
                       h, hb, msg_d, off_d, msg_s, off_s,
                       w1ut, w2ut, upb1, upb2, lng, lnb, out);
  } else {
    unsigned short* incb  = (unsigned short*)(ws);
    unsigned short* outgb = (unsigned short*)(ws + 25600000);
    float* indeg  = (float*)(ws + 51200000);
    float* outdeg = (float*)(ws + 51600000);
    short* hb     = (short*)(ws + 52000000);
    short* w1et   = (short*)(ws + 77600000);
    short* w2et   = (short*)(ws + 77698304);
    short* w1ut   = (short*)(ws + 77731072);
    short* w2ut   = (short*)(ws + 77829376);

    hipMemsetAsync(ws, 0, 52000000, stream);
    hipLaunchKernelGGL(k_prep_h, dim3(2048), dim3(256), 0, stream,
                       (const float4*)h, (short4*)hb, NNODES * 128 / 4);
    hipLaunchKernelGGL(k_prep_w, dim3(256), dim3(256), 0, stream,
                       epw1, epw2, upw1, upw2, w1et, w2et, w1ut, w2ut);
    hipLaunchKernelGGL(k_edge_at, dim3(1024), dim3(256), 0, stream,
                       hb, ei, ex, w1et, w2et, epb1, epb2, incb, outgb, indeg, outdeg);
    hipLaunchKernelGGL(k_node_at, dim3(512), dim3(256), 0, stream,
                       h, hb, incb, outgb, indeg, outdeg, w1ut, w2ut, upb1, upb2,
                       lng, lnb, out);
  }
}

// Round 9
// 793.103 us; speedup vs baseline: 1.0510x; 1.0510x over previous
//
#include <hip/hip_runtime.h>
#include <stdint.h>

#define HIDD 128
#define NNODES 100000
#define NEDGES 800000
#define NSEG 196          // ceil(100000/512) segments for the scan

typedef short s16x8 __attribute__((ext_vector_type(8)));
typedef float f32x4 __attribute__((ext_vector_type(4)));

__device__ __forceinline__ short f2bf(float f) {
  union { float f; unsigned u; } v; v.f = f;
  return (short)((v.u + 0x7fffu + ((v.u >> 16) & 1u)) >> 16);
}
__device__ __forceinline__ short4 cvt4(float4 v) {
  short4 s; s.x = f2bf(v.x); s.y = f2bf(v.y); s.z = f2bf(v.z); s.w = f2bf(v.w);
  return s;
}
__device__ __forceinline__ float bflo(unsigned w) {
  union { unsigned u; float f; } v; v.u = w << 16; return v.f;
}
__device__ __forceinline__ float bfhi(unsigned w) {
  union { unsigned u; float f; } v; v.u = w & 0xffff0000u; return v.f;
}
__device__ __forceinline__ unsigned pack2(float a, float b) {
  return ((unsigned)(unsigned short)f2bf(b) << 16) | (unsigned)(unsigned short)f2bf(a);
}
__device__ __forceinline__ f32x4 mfma16(s16x8 a, s16x8 b, f32x4 c) {
  return __builtin_amdgcn_mfma_f32_16x16x32_bf16(a, b, c, 0, 0, 0);
}
__device__ __forceinline__ void atomic_pk_bf16(unsigned short* addr, unsigned pk) {
  asm volatile("global_atomic_pk_add_bf16 %0, %1, off" :: "v"(addr), "v"(pk) : "memory");
}

// ---------- prep: h -> bf16 ----------
__global__ void k_prep_h(const float4* __restrict__ h4, short4* __restrict__ hb4, int n4) {
  int stride = gridDim.x * blockDim.x;
  for (int i = blockIdx.x * blockDim.x + threadIdx.x; i < n4; i += stride)
    hb4[i] = cvt4(h4[i]);
}

// ---------- prep: weights -> bf16 [out][in]; w2e col-permuted ----------
__global__ void k_prep_w(const float* __restrict__ w1e, const float* __restrict__ w2e,
                         const float* __restrict__ w1u, const float* __restrict__ w2u,
                         short* __restrict__ w1et, short* __restrict__ w2et,
                         short* __restrict__ w1ut, short* __restrict__ w2ut) {
  int i = blockIdx.x * 256 + threadIdx.x;
  if (i < 49152) {               // dest [128][384]: n=i/384, k=i%384
    int n = i / 384, k = i - n * 384;
    w1et[i] = f2bf(w1e[k * 128 + n]);
    w1ut[i] = f2bf(w1u[k * 128 + n]);
  } else {
    int j = i - 49152;
    if (j < 16384) {             // dest [128][128]: n=j>>7, k=j&127
      int n = j >> 7, k = j & 127;
      int oc = (n & ~31) + 2 * (n & 15) + ((n >> 4) & 1);
      w2et[j] = f2bf(w2e[k * 128 + oc]);   // permuted
      w2ut[j] = f2bf(w2u[k * 128 + n]);    // natural
    }
  }
}

// ================= counting-sort chain =================
__global__ void k_hist(const int* __restrict__ eidx, int* __restrict__ cnt_s,
                       int* __restrict__ cnt_d) {
  int i = blockIdx.x * 256 + threadIdx.x;
  if (i < NEDGES) {
    atomicAdd(&cnt_s[eidx[i]], 1);
    atomicAdd(&cnt_d[eidx[NEDGES + i]], 1);
  }
}

__global__ void k_bsum(const int* __restrict__ cnt_d, const int* __restrict__ cnt_s,
                       int* __restrict__ bsum) {
  __shared__ int red[256];
  int gb = blockIdx.x, sel = gb >= NSEG, b = gb - sel * NSEG;
  const int* cnt = sel ? cnt_s : cnt_d;
  int t = threadIdx.x;
  int i0 = b * 512 + 2 * t;
  int a = (i0 < NNODES) ? cnt[i0] : 0;
  int c = (i0 + 1 < NNODES) ? cnt[i0 + 1] : 0;
  red[t] = a + c;
  __syncthreads();
  for (int d = 128; d > 0; d >>= 1) {
    if (t < d) red[t] += red[t + d];
    __syncthreads();
  }
  if (t == 0) bsum[gb] = red[0];
}

__global__ void k_soff(int* __restrict__ bsum, int* __restrict__ off_d,
                       int* __restrict__ off_s) {
  if (threadIdx.x == 0) {
    int tot = 0;
    for (int i = 0; i < NSEG; ++i) { int v = bsum[i]; bsum[i] = tot; tot += v; }
    off_d[NNODES] = tot;
  } else if (threadIdx.x == 1) {
    int tot = 0;
    for (int i = NSEG; i < 2 * NSEG; ++i) { int v = bsum[i]; bsum[i] = tot; tot += v; }
    off_s[NNODES] = tot;
  }
}

__global__ void k_sfin(const int* __restrict__ cnt_d, const int* __restrict__ cnt_s,
                       const int* __restrict__ bsum,
                       int* __restrict__ off_d, int* __restrict__ off_s,
                       int* __restrict__ cur_d, int* __restrict__ cur_s) {
  __shared__ int p[256];
  int gb = blockIdx.x, sel = gb >= NSEG, b = gb - sel * NSEG;
  const int* cnt = sel ? cnt_s : cnt_d;
  int* off = sel ? off_s : off_d;
  int* cur = sel ? cur_s : cur_d;
  int t = threadIdx.x;
  int i0 = b * 512 + 2 * t;
  int a = (i0 < NNODES) ? cnt[i0] : 0;
  int c = (i0 + 1 < NNODES) ? cnt[i0 + 1] : 0;
  p[t] = a + c;
  __syncthreads();
  for (int d = 1; d < 256; d <<= 1) {
    int v = (t >= d) ? p[t - d] : 0;
    __syncthreads();
    p[t] += v;
    __syncthreads();
  }
  int excl = (t ? p[t - 1] : 0) + bsum[gb];
  if (i0 < NNODES)     { off[i0] = excl;     cur[i0] = excl; }
  if (i0 + 1 < NNODES) { off[i0 + 1] = excl + a; cur[i0 + 1] = excl + a; }
}

// emit per-edge CSR slot
__global__ void k_scat2(const int* __restrict__ eidx, int* __restrict__ cur_s,
                        int* __restrict__ cur_d, int* __restrict__ slot_s,
                        int* __restrict__ slot_d) {
  int i = blockIdx.x * 256 + threadIdx.x;
  if (i < NEDGES) {
    slot_s[i] = atomicAdd(&cur_s[eidx[i]], 1);
    slot_d[i] = atomicAdd(&cur_d[eidx[NEDGES + i]], 1);
  }
}

// ================= edge MLP -> messages in CSR order; 3 blocks/CU =================
// Stores are issued BEFORE bar4 so the barrier's vmcnt(0) drains all 4 waves'
// 64B segments of each 256B msg line in a tight window -> L2 write-combines
// full lines (R8 lesson: skewed partial-line stores caused 480MB of
// write-allocate re-fetch from HBM).
__global__ __launch_bounds__(256, 3)
void k_edge2(const short* __restrict__ hb, const int* __restrict__ eidx,
             const float* __restrict__ ex,
             const short* __restrict__ w1t, const short* __restrict__ w2t,
             const float* __restrict__ b1g, const float* __restrict__ b2g,
             const int* __restrict__ slot_s, const int* __restrict__ slot_d,
             unsigned* __restrict__ msg_s, unsigned* __restrict__ msg_d) {
  __shared__ __align__(16) char smem[51200];
  short (*Xh)[264] = (short (*)[264])smem;            // h[src]|h[dst], 33792 B
  short (*Xe)[136] = (short (*)[136])(smem + 33792);  // edge_x, 17408 B
  short (*Hs)[136] = (short (*)[136])(smem + 33792);  // hidden, ALIASES Xe

  const int tid = threadIdx.x;
  const int wave = tid >> 6, lane = tid & 63;
  const int lg = lane >> 4, lr = lane & 15;
  const int koff = lg * 8;
  const int c0 = wave * 32 + lr, c1 = c0 + 16;
  const int pc0 = wave * 32 + 2 * lr;   // natural col of frag0 (permuted W2)

  s16x8 wb1a[12], wb1b[12], wb2a[4], wb2b[4];
#pragma unroll
  for (int kk = 0; kk < 12; ++kk) {
    wb1a[kk] = *(const s16x8*)(w1t + c0 * 384 + kk * 32 + koff);
    wb1b[kk] = *(const s16x8*)(w1t + c1 * 384 + kk * 32 + koff);
  }
#pragma unroll
  for (int kk = 0; kk < 4; ++kk) {
    wb2a[kk] = *(const s16x8*)(w2t + c0 * 128 + kk * 32 + koff);
    wb2b[kk] = *(const s16x8*)(w2t + c1 * 128 + kk * 32 + koff);
  }
  const float bias1_0 = b1g[c0], bias1_1 = b1g[c1];
  const float bias2_0 = b2g[pc0], bias2_1 = b2g[pc0 + 1];

  for (int t = blockIdx.x; t < NEDGES / 64; t += gridDim.x) {
    const int base = t * 64;

    // Phase A: stage h and edge_x through LDS once per block (R4/R5 lesson);
    // slots in per-lane registers.
    for (int u = tid; u < 64 * 32; u += 256) {
      int r = u >> 5, c = u & 31;
      int node = (c < 16) ? eidx[base + r] : eidx[NEDGES + base + r];
      *(int4*)&Xh[r][c * 8] = *(const int4*)(hb + (long)node * 128 + (c & 15) * 8);
    }
    for (int u = tid; u < 64 * 32; u += 256) {
      int r = u >> 5, q = u & 31;
      float4 v = *(const float4*)(ex + (long)(base + r) * 128 + q * 4);
      *(short4*)&Xe[r][q * 4] = cvt4(v);
    }
    int ssl[16], sdl[16];
#pragma unroll
    for (int m = 0; m < 4; ++m)
#pragma unroll
      for (int r2 = 0; r2 < 4; ++r2) {
        int row = m * 16 + lg * 4 + r2;
        ssl[m * 4 + r2] = slot_s[base + row];
        sdl[m * 4 + r2] = slot_d[base + row];
      }
    __syncthreads();   // bar1: staging visible

    // Phase B: layer 1 (Xh: K 0..255, Xe: K 256..383)
    f32x4 acc[4][2] = {};
#pragma unroll
    for (int kk = 0; kk < 8; ++kk) {
      int k0 = kk * 32 + koff;
#pragma unroll
      for (int m = 0; m < 4; ++m) {
        s16x8 a = *(const s16x8*)&Xh[m * 16 + lr][k0];
        acc[m][0] = mfma16(a, wb1a[kk], acc[m][0]);
        acc[m][1] = mfma16(a, wb1b[kk], acc[m][1]);
      }
    }
#pragma unroll
    for (int kk = 0; kk < 4; ++kk) {
      int k0 = kk * 32 + koff;
#pragma unroll
      for (int m = 0; m < 4; ++m) {
        s16x8 a = *(const s16x8*)&Xe[m * 16 + lr][k0];
        acc[m][0] = mfma16(a, wb1a[8 + kk], acc[m][0]);
        acc[m][1] = mfma16(a, wb1b[8 + kk], acc[m][1]);
      }
    }
    __syncthreads();   // bar2: Xe reads done (Hs aliases it)

#pragma unroll
    for (int m = 0; m < 4; ++m)
#pragma unroll
      for (int r2 = 0; r2 < 4; ++r2) {
        int row = m * 16 + lg * 4 + r2;
        Hs[row][c0] = f2bf(fmaxf(acc[m][0][r2] + bias1_0, 0.f));
        Hs[row][c1] = f2bf(fmaxf(acc[m][1][r2] + bias1_1, 0.f));
      }
    __syncthreads();   // bar3: Hs ready

    // Phase C: layer 2
    f32x4 acc2[4][2] = {};
#pragma unroll
    for (int kk = 0; kk < 4; ++kk) {
      int k0 = kk * 32 + koff;
#pragma unroll
      for (int m = 0; m < 4; ++m) {
        s16x8 a = *(const s16x8*)&Hs[m * 16 + lr][k0];
        acc2[m][0] = mfma16(a, wb2a[kk], acc2[m][0]);
        acc2[m][1] = mfma16(a, wb2b[kk], acc2[m][1]);
      }
    }
    // dual CSR store BEFORE bar4 -> barrier drains segments while adjacent
#pragma unroll
    for (int m = 0; m < 4; ++m)
#pragma unroll
      for (int r2 = 0; r2 < 4; ++r2) {
        unsigned pk = pack2(acc2[m][0][r2] + bias2_0, acc2[m][1][r2] + bias2_1);
        int lo = wave * 16 + lr;
        msg_s[(long)ssl[m * 4 + r2] * 64 + lo] = pk;
        msg_d[(long)sdl[m * 4 + r2] * 64 + lo] = pk;
      }
    __syncthreads();   // bar4: drains stores; Hs reads retired
  }
}

// ================= node: streaming CSR aggregate + MLP + LN (R7-proven) =================
__global__ __launch_bounds__(256, 2)
void k_node2(const float* __restrict__ h, const short* __restrict__ hb,
             const unsigned* __restrict__ msg_d, const int* __restrict__ off_d,
             const unsigned* __restrict__ msg_s, const int* __restrict__ off_s,
             const short* __restrict__ w1t, const short* __restrict__ w2t,
             const float* __restrict__ b1g, const float* __restrict__ b2g,
             const float* __restrict__ lng, const float* __restrict__ lnb,
             float* __restrict__ out) {
  __shared__ __align__(16) char smem[67584];
  short (*Xs)[392] = (short (*)[392])smem;            // 50176 B
  float (*Xf)[132] = (float (*)[132])smem;            // overlay
  short (*Hs)[136] = (short (*)[136])(smem + 50176);  // 17408 B

  const int tid = threadIdx.x;
  const int wave = tid >> 6, lane = tid & 63;
  const int lg = lane >> 4, lr = lane & 15;
  const int koff = lg * 8;
  const int c0 = wave * 32 + lr, c1 = c0 + 16;

  s16x8 wb1a[12], wb1b[12], wb2a[4], wb2b[4];
#pragma unroll
  for (int kk = 0; kk < 12; ++kk) {
    wb1a[kk] = *(const s16x8*)(w1t + c0 * 384 + kk * 32 + koff);
    wb1b[kk] = *(const s16x8*)(w1t + c1 * 384 + kk * 32 + koff);
  }
#pragma unroll
  for (int kk = 0; kk < 4; ++kk) {
    wb2a[kk] = *(const s16x8*)(w2t + c0 * 128 + kk * 32 + koff);
    wb2b[kk] = *(const s16x8*)(w2t + c1 * 128 + kk * 32 + koff);
  }
  const float bias1_0 = b1g[c0], bias1_1 = b1g[c1];
  const float bias2_0 = b2g[c0], bias2_1 = b2g[c1];

  const int ntiles = (NNODES + 63) / 64;
  for (int t = blockIdx.x; t < ntiles; t += gridDim.x) {
    const int base = t * 64;

    for (int u = tid; u < 64 * 16; u += 256) {
      int r = u >> 4, c = u & 15;
      long node = min(base + r, NNODES - 1);
      *(int4*)&Xs[r][c * 8] = *(const int4*)(hb + node * 128 + c * 8);
    }
    {
      int r = tid >> 2, q = tid & 3;
      long node = base + r;
      bool valid = node < NNODES;
#pragma unroll
      for (int dir = 0; dir < 2; ++dir) {
        const int* off = dir ? off_s : off_d;
        const unsigned* msg = dir ? msg_s : msg_d;
        float av[32];
#pragma unroll
        for (int j = 0; j < 32; ++j) av[j] = 0.f;
        int e0 = 0, e1 = 0;
        if (valid) { e0 = off[node]; e1 = off[node + 1]; }
        for (int e = e0; e < e1; ++e) {
          const uint4* mp = (const uint4*)(msg + (long)e * 64 + q * 16);
          uint4 u0 = mp[0], u1 = mp[1], u2 = mp[2], u3 = mp[3];
          av[0]  += bflo(u0.x); av[1]  += bfhi(u0.x);
          av[2]  += bflo(u0.y); av[3]  += bfhi(u0.y);
          av[4]  += bflo(u0.z); av[5]  += bfhi(u0.z);
          av[6]  += bflo(u0.w); av[7]  += bfhi(u0.w);
          av[8]  += bflo(u1.x); av[9]  += bfhi(u1.x);
          av[10] += bflo(u1.y); av[11] += bfhi(u1.y);
          av[12] += bflo(u1.z); av[13] += bfhi(u1.z);
          av[14] += bflo(u1.w); av[15] += bfhi(u1.w);
          av[16] += bflo(u2.x); av[17] += bfhi(u2.x);
          av[18] += bflo(u2.y); av[19] += bfhi(u2.y);
          av[20] += bflo(u2.z); av[21] += bfhi(u2.z);
          av[22] += bflo(u2.w); av[23] += bfhi(u2.w);
          av[24] += bflo(u3.x); av[25] += bfhi(u3.x);
          av[26] += bflo(u3.y); av[27] += bfhi(u3.y);
          av[28] += bflo(u3.z); av[29] += bfhi(u3.z);
          av[30] += bflo(u3.w); av[31] += bfhi(u3.w);
        }
        float sc = 1.f / fmaxf((float)(e1 - e0), 1.f);
        unsigned pk[16];
#pragma unroll
        for (int j = 0; j < 16; ++j) pk[j] = pack2(av[2 * j] * sc, av[2 * j + 1] * sc);
        uint4* dst = (uint4*)&Xs[r][(dir ? 256 : 128) + q * 32];
        dst[0] = make_uint4(pk[0], pk[1], pk[2], pk[3]);
        dst[1] = make_uint4(pk[4], pk[5], pk[6], pk[7]);
        dst[2] = make_uint4(pk[8], pk[9], pk[10], pk[11]);
        dst[3] = make_uint4(pk[12], pk[13], pk[14], pk[15]);
      }
    }
    __syncthreads();

    f32x4 acc[4][2] = {};
#pragma unroll
    for (int kk = 0; kk < 12; ++kk) {
      int k0 = kk * 32 + koff;
#pragma unroll
      for (int m = 0; m < 4; ++m) {
        s16x8 a = *(const s16x8*)&Xs[m * 16 + lr][k0];
        acc[m][0] = mfma16(a, wb1a[kk], acc[m][0]);
        acc[m][1] = mfma16(a, wb1b[kk], acc[m][1]);
      }
    }
#pragma unroll
    for (int m = 0; m < 4; ++m)
#pragma unroll
      for (int r2 = 0; r2 < 4; ++r2) {
        int row = m * 16 + lg * 4 + r2;
        Hs[row][c0] = f2bf(fmaxf(acc[m][0][r2] + bias1_0, 0.f));
        Hs[row][c1] = f2bf(fmaxf(acc[m][1][r2] + bias1_1, 0.f));
      }
    __syncthreads();

    f32x4 acc2[4][2] = {};
#pragma unroll
    for (int kk = 0; kk < 4; ++kk) {
      int k0 = kk * 32 + koff;
#pragma unroll
      for (int m = 0; m < 4; ++m) {
        s16x8 a = *(const s16x8*)&Hs[m * 16 + lr][k0];
        acc2[m][0] = mfma16(a, wb2a[kk], acc2[m][0]);
        acc2[m][1] = mfma16(a, wb2b[kk], acc2[m][1]);
      }
    }
#pragma unroll
    for (int m = 0; m < 4; ++m)
#pragma unroll
      for (int r2 = 0; r2 < 4; ++r2) {
        int row = m * 16 + lg * 4 + r2;
        long node = base + row;
        float h0 = 0.f, h1 = 0.f;
        if (node < NNODES) { h0 = h[node * 128 + c0]; h1 = h[node * 128 + c1]; }
        Xf[row][c0] = acc2[m][0][r2] + bias2_0 + h0;
        Xf[row][c1] = acc2[m][1][r2] + bias2_1 + h1;
      }
    __syncthreads();

    {
      int r = tid >> 2, q = tid & 3;
      float sum = 0.f, ss = 0.f;
      float4 vals[8];
#pragma unroll
      for (int j = 0; j < 8; ++j) {
        float4 v = *(const float4*)&Xf[r][q * 32 + j * 4];
        vals[j] = v;
        sum += v.x + v.y + v.z + v.w;
        ss += v.x * v.x + v.y * v.y + v.z * v.z + v.w * v.w;
      }
      sum += __shfl_xor(sum, 1); sum += __shfl_xor(sum, 2);
      ss  += __shfl_xor(ss, 1);  ss  += __shfl_xor(ss, 2);
      float mean = sum * (1.f / 128.f);
      float var = ss * (1.f / 128.f) - mean * mean;
      float rstd = rsqrtf(var + 1e-5f);
      long node = base + r;
      if (node < NNODES) {
#pragma unroll
        for (int j = 0; j < 8; ++j) {
          int cc = q * 32 + j * 4;
          float4 v = vals[j];
          float4 o;
          o.x = (v.x - mean) * rstd * lng[cc + 0] + lnb[cc + 0];
          o.y = (v.y - mean) * rstd * lng[cc + 1] + lnb[cc + 1];
          o.z = (v.z - mean) * rstd * lng[cc + 2] + lnb[cc + 2];
          o.w = (v.w - mean) * rstd * lng[cc + 3] + lnb[cc + 3];
          *(float4*)(out + node * 128 + cc) = o;
        }
      }
    }
    __syncthreads();
  }
}

// ================= fallback path (R3, proven): pk-bf16 atomics =================
__global__ __launch_bounds__(256, 2)
void k_edge_at(const short* __restrict__ hb, const int* __restrict__ eidx,
               const float* __restrict__ ex,
               const short* __restrict__ w1t, const short* __restrict__ w2t,
               const float* __restrict__ b1g, const float* __restrict__ b2g,
               unsigned short* __restrict__ incb, unsigned short* __restrict__ outgb,
               float* __restrict__ indeg, float* __restrict__ outdeg) {
  __shared__ __align__(16) short Xs[64][392];
  __shared__ __align__(16) short Hs[64][136];
  const int tid = threadIdx.x;
  const int wave = tid >> 6, lane = tid & 63;
  const int lg = lane >> 4, lr = lane & 15;
  const int koff = lg * 8;
  const int c0 = wave * 32 + lr, c1 = c0 + 16;
  const int pc0 = wave * 32 + 2 * lr;
  s16x8 wb1a[12], wb1b[12], wb2a[4], wb2b[4];
#pragma unroll
  for (int kk = 0; kk < 12; ++kk) {
    wb1a[kk] = *(const s16x8*)(w1t + c0 * 384 + kk * 32 + koff);
    wb1b[kk] = *(const s16x8*)(w1t + c1 * 384 + kk * 32 + koff);
  }
#pragma unroll
  for (int kk = 0; kk < 4; ++kk) {
    wb2a[kk] = *(const s16x8*)(w2t + c0 * 128 + kk * 32 + koff);
    wb2b[kk] = *(const s16x8*)(w2t + c1 * 128 + kk * 32 + koff);
  }
  const float bias1_0 = b1g[c0], bias1_1 = b1g[c1];
  const float bias2_0 = b2g[pc0], bias2_1 = b2g[pc0 + 1];
  for (int t = blockIdx.x; t < NEDGES / 64; t += gridDim.x) {
    const int base = t * 64;
    for (int u = tid; u < 64 * 32; u += 256) {
      int r = u >> 5, c = u & 31;
      int node = (c < 16) ? eidx[base + r] : eidx[NEDGES + base + r];
      *(int4*)&Xs[r][c * 8] = *(const int4*)(hb + (long)node * 128 + (c & 15) * 8);
    }
    for (int u = tid; u < 64 * 32; u += 256) {
      int r = u >> 5, q = u & 31;
      float4 v = *(const float4*)(ex + (long)(base + r) * 128 + q * 4);
      *(short4*)&Xs[r][256 + q * 4] = cvt4(v);
    }
    if (tid < 64) {
      atomicAdd(&outdeg[eidx[base + tid]], 1.0f);
      atomicAdd(&indeg[eidx[NEDGES + base + tid]], 1.0f);
    }
    __syncthreads();
    f32x4 acc[4][2] = {};
#pragma unroll
    for (int kk = 0; kk < 12; ++kk) {
      int k0 = kk * 32 + koff;
#pragma unroll
      for (int m = 0; m < 4; ++m) {
        s16x8 a = *(const s16x8*)&Xs[m * 16 + lr][k0];
        acc[m][0] = mfma16(a, wb1a[kk], acc[m][0]);
        acc[m][1] = mfma16(a, wb1b[kk], acc[m][1]);
      }
    }
#pragma unroll
    for (int m = 0; m < 4; ++m)
#pragma unroll
      for (int r2 = 0; r2 < 4; ++r2) {
        int row = m * 16 + lg * 4 + r2;
        Hs[row][c0] = f2bf(fmaxf(acc[m][0][r2] + bias1_0, 0.f));
        Hs[row][c1] = f2bf(fmaxf(acc[m][1][r2] + bias1_1, 0.f));
      }
    __syncthreads();
    f32x4 acc2[4][2] = {};
#pragma unroll
    for (int kk = 0; kk < 4; ++kk) {
#pragma unroll
      for (int m = 0; m < 4; ++m) {
        s16x8 a = *(const s16x8*)&Hs[m * 16 + lr][kk * 32 + koff];
        acc2[m][0] = mfma16(a, wb2a[kk], acc2[m][0]);
        acc2[m][1] = mfma16(a, wb2b[kk], acc2[m][1]);
      }
    }
#pragma unroll
    for (int m = 0; m < 4; ++m)
#pragma unroll
      for (int r2 = 0; r2 < 4; ++r2) {
        int row = m * 16 + lg * 4 + r2;
        int s = eidx[base + row], d = eidx[NEDGES + base + row];
        unsigned pk = pack2(acc2[m][0][r2] + bias2_0, acc2[m][1][r2] + bias2_1);
        atomic_pk_bf16(outgb + (long)s * 128 + pc0, pk);
        atomic_pk_bf16(incb + (long)d * 128 + pc0, pk);
      }
  }
}

__global__ __launch_bounds__(256, 2)
void k_node_at(const float* __restrict__ h, const short* __restrict__ hb,
               const unsigned short* __restrict__ incb,
               const unsigned short* __restrict__ outgb,
               const float* __restrict__ indeg, const float* __restrict__ outdeg,
               const short* __restrict__ w1t, const short* __restrict__ w2t,
               const float* __restrict__ b1g, const float* __restrict__ b2g,
               const float* __restrict__ lng, const float* __restrict__ lnb,
               float* __restrict__ out) {
  __shared__ __align__(16) char smem[67584];
  short (*Xs)[392] = (short (*)[392])smem;
  float (*Xf)[132] = (float (*)[132])smem;
  short (*Hs)[136] = (short (*)[136])(smem + 50176);
  const int tid = threadIdx.x;
  const int wave = tid >> 6, lane = tid & 63;
  const int lg = lane >> 4, lr = lane & 15;
  const int koff = lg * 8;
  const int c0 = wave * 32 + lr, c1 = c0 + 16;
  s16x8 wb1a[12], wb1b[12], wb2a[4], wb2b[4];
#pragma unroll
  for (int kk = 0; kk < 12; ++kk) {
    wb1a[kk] = *(const s16x8*)(w1t + c0 * 384 + kk * 32 + koff);
    wb1b[kk] = *(const s16x8*)(w1t + c1 * 384 + kk * 32 + koff);
  }
#pragma unroll
  for (int kk = 0; kk < 4; ++kk) {
    wb2a[kk] = *(const s16x8*)(w2t + c0 * 128 + kk * 32 + koff);
    wb2b[kk] = *(const s16x8*)(w2t + c1 * 128 + kk * 32 + koff);
  }
  const float bias1_0 = b1g[c0], bias1_1 = b1g[c1];
  const float bias2_0 = b2g[c0], bias2_1 = b2g[c1];
  const int ntiles = (NNODES + 63) / 64;
  for (int t = blockIdx.x; t < ntiles; t += gridDim.x) {
    const int base = t * 64;
    for (int u = tid; u < 64 * 16; u += 256) {
      int r = u >> 4, c = u & 15;
      long node = min(base + r, NNODES - 1);
      *(int4*)&Xs[r][c * 8] = *(const int4*)(hb + node * 128 + c * 8);
    }
    for (int u = tid; u < 64 * 16; u += 256) {
      int r = u >> 4, c = u & 15;
      long node = min(base + r, NNODES - 1);
      float s = 1.f / fmaxf(indeg[node], 1.f);
      uint4 w = *(const uint4*)(incb + node * 128 + c * 8);
      *(uint4*)&Xs[r][128 + c * 8] = make_uint4(
        pack2(bflo(w.x) * s, bfhi(w.x) * s), pack2(bflo(w.y) * s, bfhi(w.y) * s),
        pack2(bflo(w.z) * s, bfhi(w.z) * s), pack2(bflo(w.w) * s, bfhi(w.w) * s));
    }
    for (int u = tid; u < 64 * 16; u += 256) {
      int r = u >> 4, c = u & 15;
      long node = min(base + r, NNODES - 1);
      float s = 1.f / fmaxf(outdeg[node], 1.f);
      uint4 w = *(const uint4*)(outgb + node * 128 + c * 8);
      *(uint4*)&Xs[r][256 + c * 8] = make_uint4(
        pack2(bflo(w.x) * s, bfhi(w.x) * s), pack2(bflo(w.y) * s, bfhi(w.y) * s),
        pack2(bflo(w.z) * s, bfhi(w.z) * s), pack2(bflo(w.w) * s, bfhi(w.w) * s));
    }
    __syncthreads();
    f32x4 acc[4][2] = {};
#pragma unroll
    for (int kk = 0; kk < 12; ++kk) {
      int k0 = kk * 32 + koff;
#pragma unroll
      for (int m = 0; m < 4; ++m) {
        s16x8 a = *(const s16x8*)&Xs[m * 16 + lr][k0];
        acc[m][0] = mfma16(a, wb1a[kk], acc[m][0]);
        acc[m][1] = mfma16(a, wb1b[kk], acc[m][1]);
      }
    }
#pragma unroll
    for (int m = 0; m < 4; ++m)
#pragma unroll
      for (int r2 = 0; r2 < 4; ++r2) {
        int row = m * 16 + lg * 4 + r2;
        Hs[row][c0] = f2bf(fmaxf(acc[m][0][r2] + bias1_0, 0.f));
        Hs[row][c1] = f2bf(fmaxf(acc[m][1][r2] + bias1_1, 0.f));
      }
    __syncthreads();
    f32x4 acc2[4][2] = {};
#pragma unroll
    for (int kk = 0; kk < 4; ++kk) {
      int k0 = kk * 32 + koff;
#pragma unroll
      for (int m = 0; m < 4; ++m) {
        s16x8 a = *(const s16x8*)&Hs[m * 16 + lr][k0];
        acc2[m][0] = mfma16(a, wb2a[kk], acc2[m][0]);
        acc2[m][1] = mfma16(a, wb2b[kk], acc2[m][1]);
      }
    }
#pragma unroll
    for (int m = 0; m < 4; ++m)
#pragma unroll
      for (int r2 = 0; r2 < 4; ++r2) {
        int row = m * 16 + lg * 4 + r2;
        long node = base + row;
        float h0 = 0.f, h1 = 0.f;
        if (node < NNODES) { h0 = h[node * 128 + c0]; h1 = h[node * 128 + c1]; }
        Xf[row][c0] = acc2[m][0][r2] + bias2_0 + h0;
        Xf[row][c1] = acc2[m][1][r2] + bias2_1 + h1;
      }
    __syncthreads();
    {
      int r = tid >> 2, q = tid & 3;
      float sum = 0.f, ss = 0.f;
      float4 vals[8];
#pragma unroll
      for (int j = 0; j < 8; ++j) {
        float4 v = *(const float4*)&Xf[r][q * 32 + j * 4];
        vals[j] = v;
        sum += v.x + v.y + v.z + v.w;
        ss += v.x * v.x + v.y * v.y + v.z * v.z + v.w * v.w;
      }
      sum += __shfl_xor(sum, 1); sum += __shfl_xor(sum, 2);
      ss  += __shfl_xor(ss, 1);  ss  += __shfl_xor(ss, 2);
      float mean = sum * (1.f / 128.f);
      float var = ss * (1.f / 128.f) - mean * mean;
      float rstd = rsqrtf(var + 1e-5f);
      long node = base + r;
      if (node < NNODES) {
#pragma unroll
        for (int j = 0; j < 8; ++j) {
          int cc = q * 32 + j * 4;
          float4 v = vals[j];
          float4 o;
          o.x = (v.x - mean) * rstd * lng[cc + 0] + lnb[cc + 0];
          o.y = (v.y - mean) * rstd * lng[cc + 1] + lnb[cc + 1];
          o.z = (v.z - mean) * rstd * lng[cc + 2] + lnb[cc + 2];
          o.w = (v.w - mean) * rstd * lng[cc + 3] + lnb[cc + 3];
          *(float4*)(out + node * 128 + cc) = o;
        }
      }
    }
    __syncthreads();
  }
}

extern "C" void kernel_launch(void* const* d_in, const int* in_sizes, int n_in,
                              void* d_out, int out_size, void* d_ws, size_t ws_size,
                              hipStream_t stream) {
  const float* h    = (const float*)d_in[0];
  const int*   ei   = (const int*)d_in[1];
  const float* ex   = (const float*)d_in[2];
  const float* epw1 = (const float*)d_in[3];
  const float* epb1 = (const float*)d_in[4];
  const float* epw2 = (const float*)d_in[5];
  const float* epb2 = (const float*)d_in[6];
  const float* upw1 = (const float*)d_in[7];
  const float* upb1 = (const float*)d_in[8];
  const float* upw2 = (const float*)d_in[9];
  const float* upb2 = (const float*)d_in[10];
  const float* lng  = (const float*)d_in[11];
  const float* lnb  = (const float*)d_in[12];
  float* out = (float*)d_out;
  char* ws = (char*)d_ws;

  const size_t NEED = 444300000ULL;
  if (ws_size >= NEED) {
    unsigned* msg_s = (unsigned*)(ws);                      // 204,800,000
    unsigned* msg_d = (unsigned*)(ws + 204800000);          // 204,800,000
    short* hb    = (short*)(ws + 409600000);                //  25,600,000
    short* w1et  = (short*)(ws + 435200000);
    short* w2et  = (short*)(ws + 435298304);
    short* w1ut  = (short*)(ws + 435331072);
    short* w2ut  = (short*)(ws + 435429376);
    int* cnt_d   = (int*)(ws + 435462144);
    int* cnt_s   = (int*)(ws + 435862144);
    int* off_d   = (int*)(ws + 436262144);
    int* off_s   = (int*)(ws + 436662148);
    int* cur_d   = (int*)(ws + 437062152);
    int* cur_s   = (int*)(ws + 437462152);
    int* slot_s  = (int*)(ws + 437862152);
    int* slot_d  = (int*)(ws + 441062152);
    int* bsum    = (int*)(ws + 444262152);

    hipMemsetAsync(cnt_d, 0, 800000, stream);               // cnt_d + cnt_s
    hipLaunchKernelGGL(k_prep_h, dim3(2048), dim3(256), 0, stream,
                       (const float4*)h, (short4*)hb, NNODES * 128 / 4);
    hipLaunchKernelGGL(k_prep_w, dim3(256), dim3(256), 0, stream,
                       epw1, epw2, upw1, upw2, w1et, w2et, w1ut, w2ut);
    hipLaunchKernelGGL(k_hist, dim3((NEDGES + 255) / 256), dim3(256), 0, stream,
                       ei, cnt_s, cnt_d);
    hipLaunchKernelGGL(k_bsum, dim3(2 * NSEG), dim3(256), 0, stream,
                       cnt_d, cnt_s, bsum);
    hipLaunchKernelGGL(k_soff, dim3(1), dim3(64), 0, stream, bsum, off_d, off_s);
    hipLaunchKernelGGL(k_sfin, dim3(2 * NSEG), dim3(256), 0, stream,
                       cnt_d, cnt_s, bsum, off_d, off_s, cur_d, cur_s);
    hipLaunchKernelGGL(k_scat2, dim3((NEDGES + 255) / 256), dim3(256), 0, stream,
                       ei, cur_s, cur_d, slot_s, slot_d);
    hipLaunchKernelGGL(k_edge2, dim3(768), dim3(256), 0, stream,
                       hb, ei, ex, w1et, w2et, epb1, epb2, slot_s, slot_d,
                       msg_s, msg_d);
    hipLaunchKernelGGL(k_node2, dim3(512), dim3(256), 0, stream,
                       h, hb, msg_d, off_d, msg_s, off_s,
                       w1ut, w2ut, upb1, upb2, lng, lnb, out);
  } else {
    unsigned short* incb  = (unsigned short*)(ws);
    unsigned short* outgb = (unsigned short*)(ws + 25600000);
    float* indeg  = (float*)(ws + 51200000);
    float* outdeg = (float*)(ws + 51600000);
    short* hb     = (short*)(ws + 52000000);
    short* w1et   = (short*)(ws + 77600000);
    short* w2et   = (short*)(ws + 77698304);
    short* w1ut   = (short*)(ws + 77731072);
    short* w2ut   = (short*)(ws + 77829376);

    hipMemsetAsync(ws, 0, 52000000, stream);
    hipLaunchKernelGGL(k_prep_h, dim3(2048), dim3(256), 0, stream,
                       (const float4*)h, (short4*)hb, NNODES * 128 / 4);
    hipLaunchKernelGGL(k_prep_w, dim3(256), dim3(256), 0, stream,
                       epw1, epw2, upw1, upw2, w1et, w2et, w1ut, w2ut);
    hipLaunchKernelGGL(k_edge_at, dim3(1024), dim3(256), 0, stream,
                       hb, ei, ex, w1et, w2et, epb1, epb2, incb, outgb, indeg, outdeg);
    hipLaunchKernelGGL(k_node_at, dim3(512), dim3(256), 0, stream,
                       h, hb, incb, outgb, indeg, outdeg, w1ut, w2ut, upb1, upb2,
                       lng, lnb, out);
  }
}

// Round 10
// 750.815 us; speedup vs baseline: 1.1102x; 1.0563x over previous
//
#include <hip/hip_runtime.h>
#include <stdint.h>

#define HIDD 128
#define NNODES 100000
#define NEDGES 800000
#define NSEG 196          // ceil(100000/512) segments for the scan

typedef short s16x8 __attribute__((ext_vector_type(8)));
typedef float f32x4 __attribute__((ext_vector_type(4)));

__device__ __forceinline__ short f2bf(float f) {
  union { float f; unsigned u; } v; v.f = f;
  return (short)((v.u + 0x7fffu + ((v.u >> 16) & 1u)) >> 16);
}
__device__ __forceinline__ short4 cvt4(float4 v) {
  short4 s; s.x = f2bf(v.x); s.y = f2bf(v.y); s.z = f2bf(v.z); s.w = f2bf(v.w);
  return s;
}
__device__ __forceinline__ float bflo(unsigned w) {
  union { unsigned u; float f; } v; v.u = w << 16; return v.f;
}
__device__ __forceinline__ float bfhi(unsigned w) {
  union { unsigned u; float f; } v; v.u = w & 0xffff0000u; return v.f;
}
__device__ __forceinline__ unsigned pack2(float a, float b) {
  return ((unsigned)(unsigned short)f2bf(b) << 16) | (unsigned)(unsigned short)f2bf(a);
}
__device__ __forceinline__ f32x4 mfma16(s16x8 a, s16x8 b, f32x4 c) {
  return __builtin_amdgcn_mfma_f32_16x16x32_bf16(a, b, c, 0, 0, 0);
}
__device__ __forceinline__ void atomic_pk_bf16(unsigned short* addr, unsigned pk) {
  asm volatile("global_atomic_pk_add_bf16 %0, %1, off" :: "v"(addr), "v"(pk) : "memory");
}

// ---------- prep: h -> bf16 ----------
__global__ void k_prep_h(const float4* __restrict__ h4, short4* __restrict__ hb4, int n4) {
  int stride = gridDim.x * blockDim.x;
  for (int i = blockIdx.x * blockDim.x + threadIdx.x; i < n4; i += stride)
    hb4[i] = cvt4(h4[i]);
}

// ---------- prep: weights -> bf16 [out][in]; w2e col-permuted ----------
__global__ void k_prep_w(const float* __restrict__ w1e, const float* __restrict__ w2e,
                         const float* __restrict__ w1u, const float* __restrict__ w2u,
                         short* __restrict__ w1et, short* __restrict__ w2et,
                         short* __restrict__ w1ut, short* __restrict__ w2ut) {
  int i = blockIdx.x * 256 + threadIdx.x;
  if (i < 49152) {               // dest [128][384]: n=i/384, k=i%384
    int n = i / 384, k = i - n * 384;
    w1et[i] = f2bf(w1e[k * 128 + n]);
    w1ut[i] = f2bf(w1u[k * 128 + n]);
  } else {
    int j = i - 49152;
    if (j < 16384) {             // dest [128][128]: n=j>>7, k=j&127
      int n = j >> 7, k = j & 127;
      int oc = (n & ~31) + 2 * (n & 15) + ((n >> 4) & 1);
      w2et[j] = f2bf(w2e[k * 128 + oc]);   // permuted
      w2ut[j] = f2bf(w2u[k * 128 + n]);    // natural
    }
  }
}

// ================= counting-sort chain =================
__global__ void k_hist(const int* __restrict__ eidx, int* __restrict__ cnt_s,
                       int* __restrict__ cnt_d) {
  int i = blockIdx.x * 256 + threadIdx.x;
  if (i < NEDGES) {
    atomicAdd(&cnt_s[eidx[i]], 1);
    atomicAdd(&cnt_d[eidx[NEDGES + i]], 1);
  }
}

__global__ void k_bsum(const int* __restrict__ cnt_d, const int* __restrict__ cnt_s,
                       int* __restrict__ bsum) {
  __shared__ int red[256];
  int gb = blockIdx.x, sel = gb >= NSEG, b = gb - sel * NSEG;
  const int* cnt = sel ? cnt_s : cnt_d;
  int t = threadIdx.x;
  int i0 = b * 512 + 2 * t;
  int a = (i0 < NNODES) ? cnt[i0] : 0;
  int c = (i0 + 1 < NNODES) ? cnt[i0 + 1] : 0;
  red[t] = a + c;
  __syncthreads();
  for (int d = 128; d > 0; d >>= 1) {
    if (t < d) red[t] += red[t + d];
    __syncthreads();
  }
  if (t == 0) bsum[gb] = red[0];
}

__global__ void k_soff(int* __restrict__ bsum, int* __restrict__ off_d,
                       int* __restrict__ off_s) {
  if (threadIdx.x == 0) {
    int tot = 0;
    for (int i = 0; i < NSEG; ++i) { int v = bsum[i]; bsum[i] = tot; tot += v; }
    off_d[NNODES] = tot;
  } else if (threadIdx.x == 1) {
    int tot = 0;
    for (int i = NSEG; i < 2 * NSEG; ++i) { int v = bsum[i]; bsum[i] = tot; tot += v; }
    off_s[NNODES] = tot;
  }
}

__global__ void k_sfin(const int* __restrict__ cnt_d, const int* __restrict__ cnt_s,
                       const int* __restrict__ bsum,
                       int* __restrict__ off_d, int* __restrict__ off_s,
                       int* __restrict__ cur_d, int* __restrict__ cur_s) {
  __shared__ int p[256];
  int gb = blockIdx.x, sel = gb >= NSEG, b = gb - sel * NSEG;
  const int* cnt = sel ? cnt_s : cnt_d;
  int* off = sel ? off_s : off_d;
  int* cur = sel ? cur_s : cur_d;
  int t = threadIdx.x;
  int i0 = b * 512 + 2 * t;
  int a = (i0 < NNODES) ? cnt[i0] : 0;
  int c = (i0 + 1 < NNODES) ? cnt[i0 + 1] : 0;
  p[t] = a + c;
  __syncthreads();
  for (int d = 1; d < 256; d <<= 1) {
    int v = (t >= d) ? p[t - d] : 0;
    __syncthreads();
    p[t] += v;
    __syncthreads();
  }
  int excl = (t ? p[t - 1] : 0) + bsum[gb];
  if (i0 < NNODES)     { off[i0] = excl;     cur[i0] = excl; }
  if (i0 + 1 < NNODES) { off[i0 + 1] = excl + a; cur[i0 + 1] = excl + a; }
}

// emit per-edge CSR slot
__global__ void k_scat2(const int* __restrict__ eidx, int* __restrict__ cur_s,
                        int* __restrict__ cur_d, int* __restrict__ slot_s,
                        int* __restrict__ slot_d) {
  int i = blockIdx.x * 256 + threadIdx.x;
  if (i < NEDGES) {
    slot_s[i] = atomicAdd(&cur_s[eidx[i]], 1);
    slot_d[i] = atomicAdd(&cur_d[eidx[NEDGES + i]], 1);
  }
}

// ================= edge MLP -> messages in CSR order; 3 blocks/CU =================
// R10: messages transposed through LDS so ONE wave stores ONE full 256B row
// per instruction (64 lanes x 4B contiguous). R8/R9 lesson: rows assembled
// from 4 waves' 64B segments caused ~480MB of L2 write-allocate re-fetch.
__global__ __launch_bounds__(256, 3)
void k_edge2(const short* __restrict__ hb, const int* __restrict__ eidx,
             const float* __restrict__ ex,
             const short* __restrict__ w1t, const short* __restrict__ w2t,
             const float* __restrict__ b1g, const float* __restrict__ b2g,
             const int* __restrict__ slot_s, const int* __restrict__ slot_d,
             unsigned* __restrict__ msg_s, unsigned* __restrict__ msg_d) {
  __shared__ __align__(16) char smem[51712];
  short (*Xh)[264]   = (short (*)[264])smem;            // h[src]|h[dst], 33792 B
  short (*Xe)[136]   = (short (*)[136])(smem + 33792);  // edge_x, 17408 B
  short (*Hs)[136]   = (short (*)[136])(smem + 33792);  // hidden, aliases Xe
  unsigned (*Pb)[64] = (unsigned (*)[64])(smem + 33792);// packed msg, aliases Hs (16384 B)
  int* Ss = (int*)(smem + 51200);                       // 256 B
  int* Sd = (int*)(smem + 51456);                       // 256 B

  const int tid = threadIdx.x;
  const int wave = tid >> 6, lane = tid & 63;
  const int lg = lane >> 4, lr = lane & 15;
  const int koff = lg * 8;
  const int c0 = wave * 32 + lr, c1 = c0 + 16;
  const int pc0 = wave * 32 + 2 * lr;   // natural col of frag0 (permuted W2)

  s16x8 wb1a[12], wb1b[12], wb2a[4], wb2b[4];
#pragma unroll
  for (int kk = 0; kk < 12; ++kk) {
    wb1a[kk] = *(const s16x8*)(w1t + c0 * 384 + kk * 32 + koff);
    wb1b[kk] = *(const s16x8*)(w1t + c1 * 384 + kk * 32 + koff);
  }
#pragma unroll
  for (int kk = 0; kk < 4; ++kk) {
    wb2a[kk] = *(const s16x8*)(w2t + c0 * 128 + kk * 32 + koff);
    wb2b[kk] = *(const s16x8*)(w2t + c1 * 128 + kk * 32 + koff);
  }
  const float bias1_0 = b1g[c0], bias1_1 = b1g[c1];
  const float bias2_0 = b2g[pc0], bias2_1 = b2g[pc0 + 1];

  for (int t = blockIdx.x; t < NEDGES / 64; t += gridDim.x) {
    const int base = t * 64;

    // Phase A: stage h and edge_x through LDS once per block (R4/R5 lesson)
    for (int u = tid; u < 64 * 32; u += 256) {
      int r = u >> 5, c = u & 31;
      int node = (c < 16) ? eidx[base + r] : eidx[NEDGES + base + r];
      *(int4*)&Xh[r][c * 8] = *(const int4*)(hb + (long)node * 128 + (c & 15) * 8);
    }
    for (int u = tid; u < 64 * 32; u += 256) {
      int r = u >> 5, q = u & 31;
      float4 v = *(const float4*)(ex + (long)(base + r) * 128 + q * 4);
      *(short4*)&Xe[r][q * 4] = cvt4(v);
    }
    if (tid < 64) Ss[tid] = slot_s[base + tid];
    else if (tid < 128) Sd[tid - 64] = slot_d[base + tid - 64];
    __syncthreads();   // bar1: staging visible

    // Phase B: layer 1 (Xh: K 0..255, Xe: K 256..383)
    f32x4 acc[4][2] = {};
#pragma unroll
    for (int kk = 0; kk < 8; ++kk) {
      int k0 = kk * 32 + koff;
#pragma unroll
      for (int m = 0; m < 4; ++m) {
        s16x8 a = *(const s16x8*)&Xh[m * 16 + lr][k0];
        acc[m][0] = mfma16(a, wb1a[kk], acc[m][0]);
        acc[m][1] = mfma16(a, wb1b[kk], acc[m][1]);
      }
    }
#pragma unroll
    for (int kk = 0; kk < 4; ++kk) {
      int k0 = kk * 32 + koff;
#pragma unroll
      for (int m = 0; m < 4; ++m) {
        s16x8 a = *(const s16x8*)&Xe[m * 16 + lr][k0];
        acc[m][0] = mfma16(a, wb1a[8 + kk], acc[m][0]);
        acc[m][1] = mfma16(a, wb1b[8 + kk], acc[m][1]);
      }
    }
    __syncthreads();   // bar2: Xe reads done (Hs aliases it)

#pragma unroll
    for (int m = 0; m < 4; ++m)
#pragma unroll
      for (int r2 = 0; r2 < 4; ++r2) {
        int row = m * 16 + lg * 4 + r2;
        Hs[row][c0] = f2bf(fmaxf(acc[m][0][r2] + bias1_0, 0.f));
        Hs[row][c1] = f2bf(fmaxf(acc[m][1][r2] + bias1_1, 0.f));
      }
    __syncthreads();   // bar3: Hs ready

    // Phase C: layer 2
    f32x4 acc2[4][2] = {};
#pragma unroll
    for (int kk = 0; kk < 4; ++kk) {
      int k0 = kk * 32 + koff;
#pragma unroll
      for (int m = 0; m < 4; ++m) {
        s16x8 a = *(const s16x8*)&Hs[m * 16 + lr][k0];
        acc2[m][0] = mfma16(a, wb2a[kk], acc2[m][0]);
        acc2[m][1] = mfma16(a, wb2b[kk], acc2[m][1]);
      }
    }
    __syncthreads();   // bar4: Hs reads retired; Pb may overwrite

    // transpose packed messages into LDS (Pb aliases Hs)
#pragma unroll
    for (int m = 0; m < 4; ++m)
#pragma unroll
      for (int r2 = 0; r2 < 4; ++r2) {
        int row = m * 16 + lg * 4 + r2;
        Pb[row][wave * 16 + lr] = pack2(acc2[m][0][r2] + bias2_0,
                                        acc2[m][1][r2] + bias2_1);
      }
    __syncthreads();   // bar5: Pb ready

    // full-row stores: wave w stores rows w*16..w*16+15, 256B/instruction
#pragma unroll
    for (int i = 0; i < 16; ++i) {
      int row = wave * 16 + i;
      unsigned v = Pb[row][lane];
      msg_s[(long)Ss[row] * 64 + lane] = v;
      msg_d[(long)Sd[row] * 64 + lane] = v;
    }
    __syncthreads();   // bar6: Pb/Ss/Sd reads done before next tile's staging
  }
}

// ================= node: streaming CSR aggregate + MLP + LN (R7-proven) =================
__global__ __launch_bounds__(256, 2)
void k_node2(const float* __restrict__ h, const short* __restrict__ hb,
             const unsigned* __restrict__ msg_d, const int* __restrict__ off_d,
             const unsigned* __restrict__ msg_s, const int* __restrict__ off_s,
             const short* __restrict__ w1t, const short* __restrict__ w2t,
             const float* __restrict__ b1g, const float* __restrict__ b2g,
             const float* __restrict__ lng, const float* __restrict__ lnb,
             float* __restrict__ out) {
  __shared__ __align__(16) char smem[67584];
  short (*Xs)[392] = (short (*)[392])smem;            // 50176 B
  float (*Xf)[132] = (float (*)[132])smem;            // overlay
  short (*Hs)[136] = (short (*)[136])(smem + 50176);  // 17408 B

  const int tid = threadIdx.x;
  const int wave = tid >> 6, lane = tid & 63;
  const int lg = lane >> 4, lr = lane & 15;
  const int koff = lg * 8;
  const int c0 = wave * 32 + lr, c1 = c0 + 16;

  s16x8 wb1a[12], wb1b[12], wb2a[4], wb2b[4];
#pragma unroll
  for (int kk = 0; kk < 12; ++kk) {
    wb1a[kk] = *(const s16x8*)(w1t + c0 * 384 + kk * 32 + koff);
    wb1b[kk] = *(const s16x8*)(w1t + c1 * 384 + kk * 32 + koff);
  }
#pragma unroll
  for (int kk = 0; kk < 4; ++kk) {
    wb2a[kk] = *(const s16x8*)(w2t + c0 * 128 + kk * 32 + koff);
    wb2b[kk] = *(const s16x8*)(w2t + c1 * 128 + kk * 32 + koff);
  }
  const float bias1_0 = b1g[c0], bias1_1 = b1g[c1];
  const float bias2_0 = b2g[c0], bias2_1 = b2g[c1];

  const int ntiles = (NNODES + 63) / 64;
  for (int t = blockIdx.x; t < ntiles; t += gridDim.x) {
    const int base = t * 64;

    for (int u = tid; u < 64 * 16; u += 256) {
      int r = u >> 4, c = u & 15;
      long node = min(base + r, NNODES - 1);
      *(int4*)&Xs[r][c * 8] = *(const int4*)(hb + node * 128 + c * 8);
    }
    {
      int r = tid >> 2, q = tid & 3;
      long node = base + r;
      bool valid = node < NNODES;
#pragma unroll
      for (int dir = 0; dir < 2; ++dir) {
        const int* off = dir ? off_s : off_d;
        const unsigned* msg = dir ? msg_s : msg_d;
        float av[32];
#pragma unroll
        for (int j = 0; j < 32; ++j) av[j] = 0.f;
        int e0 = 0, e1 = 0;
        if (valid) { e0 = off[node]; e1 = off[node + 1]; }
        for (int e = e0; e < e1; ++e) {
          const uint4* mp = (const uint4*)(msg + (long)e * 64 + q * 16);
          uint4 u0 = mp[0], u1 = mp[1], u2 = mp[2], u3 = mp[3];
          av[0]  += bflo(u0.x); av[1]  += bfhi(u0.x);
          av[2]  += bflo(u0.y); av[3]  += bfhi(u0.y);
          av[4]  += bflo(u0.z); av[5]  += bfhi(u0.z);
          av[6]  += bflo(u0.w); av[7]  += bfhi(u0.w);
          av[8]  += bflo(u1.x); av[9]  += bfhi(u1.x);
          av[10] += bflo(u1.y); av[11] += bfhi(u1.y);
          av[12] += bflo(u1.z); av[13] += bfhi(u1.z);
          av[14] += bflo(u1.w); av[15] += bfhi(u1.w);
          av[16] += bflo(u2.x); av[17] += bfhi(u2.x);
          av[18] += bflo(u2.y); av[19] += bfhi(u2.y);
          av[20] += bflo(u2.z); av[21] += bfhi(u2.z);
          av[22] += bflo(u2.w); av[23] += bfhi(u2.w);
          av[24] += bflo(u3.x); av[25] += bfhi(u3.x);
          av[26] += bflo(u3.y); av[27] += bfhi(u3.y);
          av[28] += bflo(u3.z); av[29] += bfhi(u3.z);
          av[30] += bflo(u3.w); av[31] += bfhi(u3.w);
        }
        float sc = 1.f / fmaxf((float)(e1 - e0), 1.f);
        unsigned pk[16];
#pragma unroll
        for (int j = 0; j < 16; ++j) pk[j] = pack2(av[2 * j] * sc, av[2 * j + 1] * sc);
        uint4* dst = (uint4*)&Xs[r][(dir ? 256 : 128) + q * 32];
        dst[0] = make_uint4(pk[0], pk[1], pk[2], pk[3]);
        dst[1] = make_uint4(pk[4], pk[5], pk[6], pk[7]);
        dst[2] = make_uint4(pk[8], pk[9], pk[10], pk[11]);
        dst[3] = make_uint4(pk[12], pk[13], pk[14], pk[15]);
      }
    }
    __syncthreads();

    f32x4 acc[4][2] = {};
#pragma unroll
    for (int kk = 0; kk < 12; ++kk) {
      int k0 = kk * 32 + koff;
#pragma unroll
      for (int m = 0; m < 4; ++m) {
        s16x8 a = *(const s16x8*)&Xs[m * 16 + lr][k0];
        acc[m][0] = mfma16(a, wb1a[kk], acc[m][0]);
        acc[m][1] = mfma16(a, wb1b[kk], acc[m][1]);
      }
    }
#pragma unroll
    for (int m = 0; m < 4; ++m)
#pragma unroll
      for (int r2 = 0; r2 < 4; ++r2) {
        int row = m * 16 + lg * 4 + r2;
        Hs[row][c0] = f2bf(fmaxf(acc[m][0][r2] + bias1_0, 0.f));
        Hs[row][c1] = f2bf(fmaxf(acc[m][1][r2] + bias1_1, 0.f));
      }
    __syncthreads();

    f32x4 acc2[4][2] = {};
#pragma unroll
    for (int kk = 0; kk < 4; ++kk) {
      int k0 = kk * 32 + koff;
#pragma unroll
      for (int m = 0; m < 4; ++m) {
        s16x8 a = *(const s16x8*)&Hs[m * 16 + lr][k0];
        acc2[m][0] = mfma16(a, wb2a[kk], acc2[m][0]);
        acc2[m][1] = mfma16(a, wb2b[kk], acc2[m][1]);
      }
    }
#pragma unroll
    for (int m = 0; m < 4; ++m)
#pragma unroll
      for (int r2 = 0; r2 < 4; ++r2) {
        int row = m * 16 + lg * 4 + r2;
        long node = base + row;
        float h0 = 0.f, h1 = 0.f;
        if (node < NNODES) { h0 = h[node * 128 + c0]; h1 = h[node * 128 + c1]; }
        Xf[row][c0] = acc2[m][0][r2] + bias2_0 + h0;
        Xf[row][c1] = acc2[m][1][r2] + bias2_1 + h1;
      }
    __syncthreads();

    {
      int r = tid >> 2, q = tid & 3;
      float sum = 0.f, ss = 0.f;
      float4 vals[8];
#pragma unroll
      for (int j = 0; j < 8; ++j) {
        float4 v = *(const float4*)&Xf[r][q * 32 + j * 4];
        vals[j] = v;
        sum += v.x + v.y + v.z + v.w;
        ss += v.x * v.x + v.y * v.y + v.z * v.z + v.w * v.w;
      }
      sum += __shfl_xor(sum, 1); sum += __shfl_xor(sum, 2);
      ss  += __shfl_xor(ss, 1);  ss  += __shfl_xor(ss, 2);
      float mean = sum * (1.f / 128.f);
      float var = ss * (1.f / 128.f) - mean * mean;
      float rstd = rsqrtf(var + 1e-5f);
      long node = base + r;
      if (node < NNODES) {
#pragma unroll
        for (int j = 0; j < 8; ++j) {
          int cc = q * 32 + j * 4;
          float4 v = vals[j];
          float4 o;
          o.x = (v.x - mean) * rstd * lng[cc + 0] + lnb[cc + 0];
          o.y = (v.y - mean) * rstd * lng[cc + 1] + lnb[cc + 1];
          o.z = (v.z - mean) * rstd * lng[cc + 2] + lnb[cc + 2];
          o.w = (v.w - mean) * rstd * lng[cc + 3] + lnb[cc + 3];
          *(float4*)(out + node * 128 + cc) = o;
        }
      }
    }
    __syncthreads();
  }
}

// ================= fallback path (R3, proven): pk-bf16 atomics =================
__global__ __launch_bounds__(256, 2)
void k_edge_at(const short* __restrict__ hb, const int* __restrict__ eidx,
               const float* __restrict__ ex,
               const short* __restrict__ w1t, const short* __restrict__ w2t,
               const float* __restrict__ b1g, const float* __restrict__ b2g,
               unsigned short* __restrict__ incb, unsigned short* __restrict__ outgb,
               float* __restrict__ indeg, float* __restrict__ outdeg) {
  __shared__ __align__(16) short Xs[64][392];
  __shared__ __align__(16) short Hs[64][136];
  const int tid = threadIdx.x;
  const int wave = tid >> 6, lane = tid & 63;
  const int lg = lane >> 4, lr = lane & 15;
  const int koff = lg * 8;
  const int c0 = wave * 32 + lr, c1 = c0 + 16;
  const int pc0 = wave * 32 + 2 * lr;
  s16x8 wb1a[12], wb1b[12], wb2a[4], wb2b[4];
#pragma unroll
  for (int kk = 0; kk < 12; ++kk) {
    wb1a[kk] = *(const s16x8*)(w1t + c0 * 384 + kk * 32 + koff);
    wb1b[kk] = *(const s16x8*)(w1t + c1 * 384 + kk * 32 + koff);
  }
#pragma unroll
  for (int kk = 0; kk < 4; ++kk) {
    wb2a[kk] = *(const s16x8*)(w2t + c0 * 128 + kk * 32 + koff);
    wb2b[kk] = *(const s16x8*)(w2t + c1 * 128 + kk * 32 + koff);
  }
  const float bias1_0 = b1g[c0], bias1_1 = b1g[c1];
  const float bias2_0 = b2g[pc0], bias2_1 = b2g[pc0 + 1];
  for (int t = blockIdx.x; t < NEDGES / 64; t += gridDim.x) {
    const int base = t * 64;
    for (int u = tid; u < 64 * 32; u += 256) {
      int r = u >> 5, c = u & 31;
      int node = (c < 16) ? eidx[base + r] : eidx[NEDGES + base + r];
      *(int4*)&Xs[r][c * 8] = *(const int4*)(hb + (long)node * 128 + (c & 15) * 8);
    }
    for (int u = tid; u < 64 * 32; u += 256) {
      int r = u >> 5, q = u & 31;
      float4 v = *(const float4*)(ex + (long)(base + r) * 128 + q * 4);
      *(short4*)&Xs[r][256 + q * 4] = cvt4(v);
    }
    if (tid < 64) {
      atomicAdd(&outdeg[eidx[base + tid]], 1.0f);
      atomicAdd(&indeg[eidx[NEDGES + base + tid]], 1.0f);
    }
    __syncthreads();
    f32x4 acc[4][2] = {};
#pragma unroll
    for (int kk = 0; kk < 12; ++kk) {
      int k0 = kk * 32 + koff;
#pragma unroll
      for (int m = 0; m < 4; ++m) {
        s16x8 a = *(const s16x8*)&Xs[m * 16 + lr][k0];
        acc[m][0] = mfma16(a, wb1a[kk], acc[m][0]);
        acc[m][1] = mfma16(a, wb1b[kk], acc[m][1]);
      }
    }
#pragma unroll
    for (int m = 0; m < 4; ++m)
#pragma unroll
      for (int r2 = 0; r2 < 4; ++r2) {
        int row = m * 16 + lg * 4 + r2;
        Hs[row][c0] = f2bf(fmaxf(acc[m][0][r2] + bias1_0, 0.f));
        Hs[row][c1] = f2bf(fmaxf(acc[m][1][r2] + bias1_1, 0.f));
      }
    __syncthreads();
    f32x4 acc2[4][2] = {};
#pragma unroll
    for (int kk = 0; kk < 4; ++kk) {
#pragma unroll
      for (int m = 0; m < 4; ++m) {
        s16x8 a = *(const s16x8*)&Hs[m * 16 + lr][kk * 32 + koff];
        acc2[m][0] = mfma16(a, wb2a[kk], acc2[m][0]);
        acc2[m][1] = mfma16(a, wb2b[kk], acc2[m][1]);
      }
    }
#pragma unroll
    for (int m = 0; m < 4; ++m)
#pragma unroll
      for (int r2 = 0; r2 < 4; ++r2) {
        int row = m * 16 + lg * 4 + r2;
        int s = eidx[base + row], d = eidx[NEDGES + base + row];
        unsigned pk = pack2(acc2[m][0][r2] + bias2_0, acc2[m][1][r2] + bias2_1);
        atomic_pk_bf16(outgb + (long)s * 128 + pc0, pk);
        atomic_pk_bf16(incb + (long)d * 128 + pc0, pk);
      }
  }
}

__global__ __launch_bounds__(256, 2)
void k_node_at(const float* __restrict__ h, const short* __restrict__ hb,
               const unsigned short* __restrict__ incb,
               const unsigned short* __restrict__ outgb,
               const float* __restrict__ indeg, const float* __restrict__ outdeg,
               const short* __restrict__ w1t, const short* __restrict__ w2t,
               const float* __restrict__ b1g, const float* __restrict__ b2g,
               const float* __restrict__ lng, const float* __restrict__ lnb,
               float* __restrict__ out) {
  __shared__ __align__(16) char smem[67584];
  short (*Xs)[392] = (short (*)[392])smem;
  float (*Xf)[132] = (float (*)[132])smem;
  short (*Hs)[136] = (short (*)[136])(smem + 50176);
  const int tid = threadIdx.x;
  const int wave = tid >> 6, lane = tid & 63;
  const int lg = lane >> 4, lr = lane & 15;
  const int koff = lg * 8;
  const int c0 = wave * 32 + lr, c1 = c0 + 16;
  s16x8 wb1a[12], wb1b[12], wb2a[4], wb2b[4];
#pragma unroll
  for (int kk = 0; kk < 12; ++kk) {
    wb1a[kk] = *(const s16x8*)(w1t + c0 * 384 + kk * 32 + koff);
    wb1b[kk] = *(const s16x8*)(w1t + c1 * 384 + kk * 32 + koff);
  }
#pragma unroll
  for (int kk = 0; kk < 4; ++kk) {
    wb2a[kk] = *(const s16x8*)(w2t + c0 * 128 + kk * 32 + koff);
    wb2b[kk] = *(const s16x8*)(w2t + c1 * 128 + kk * 32 + koff);
  }
  const float bias1_0 = b1g[c0], bias1_1 = b1g[c1];
  const float bias2_0 = b2g[c0], bias2_1 = b2g[c1];
  const int ntiles = (NNODES + 63) / 64;
  for (int t = blockIdx.x; t < ntiles; t += gridDim.x) {
    const int base = t * 64;
    for (int u = tid; u < 64 * 16; u += 256) {
      int r = u >> 4, c = u & 15;
      long node = min(base + r, NNODES - 1);
      *(int4*)&Xs[r][c * 8] = *(const int4*)(hb + node * 128 + c * 8);
    }
    for (int u = tid; u < 64 * 16; u += 256) {
      int r = u >> 4, c = u & 15;
      long node = min(base + r, NNODES - 1);
      float s = 1.f / fmaxf(indeg[node], 1.f);
      uint4 w = *(const uint4*)(incb + node * 128 + c * 8);
      *(uint4*)&Xs[r][128 + c * 8] = make_uint4(
        pack2(bflo(w.x) * s, bfhi(w.x) * s), pack2(bflo(w.y) * s, bfhi(w.y) * s),
        pack2(bflo(w.z) * s, bfhi(w.z) * s), pack2(bflo(w.w) * s, bfhi(w.w) * s));
    }
    for (int u = tid; u < 64 * 16; u += 256) {
      int r = u >> 4, c = u & 15;
      long node = min(base + r, NNODES - 1);
      float s = 1.f / fmaxf(outdeg[node], 1.f);
      uint4 w = *(const uint4*)(outgb + node * 128 + c * 8);
      *(uint4*)&Xs[r][256 + c * 8] = make_uint4(
        pack2(bflo(w.x) * s, bfhi(w.x) * s), pack2(bflo(w.y) * s, bfhi(w.y) * s),
        pack2(bflo(w.z) * s, bfhi(w.z) * s), pack2(bflo(w.w) * s, bfhi(w.w) * s));
    }
    __syncthreads();
    f32x4 acc[4][2] = {};
#pragma unroll
    for (int kk = 0; kk < 12; ++kk) {
      int k0 = kk * 32 + koff;
#pragma unroll
      for (int m = 0; m < 4; ++m) {
        s16x8 a = *(const s16x8*)&Xs[m * 16 + lr][k0];
        acc[m][0] = mfma16(a, wb1a[kk], acc[m][0]);
        acc[m][1] = mfma16(a, wb1b[kk], acc[m][1]);
      }
    }
#pragma unroll
    for (int m = 0; m < 4; ++m)
#pragma unroll
      for (int r2 = 0; r2 < 4; ++r2) {
        int row = m * 16 + lg * 4 + r2;
        Hs[row][c0] = f2bf(fmaxf(acc[m][0][r2] + bias1_0, 0.f));
        Hs[row][c1] = f2bf(fmaxf(acc[m][1][r2] + bias1_1, 0.f));
      }
    __syncthreads();
    f32x4 acc2[4][2] = {};
#pragma unroll
    for (int kk = 0; kk < 4; ++kk) {
      int k0 = kk * 32 + koff;
#pragma unroll
      for (int m = 0; m < 4; ++m) {
        s16x8 a = *(const s16x8*)&Hs[m * 16 + lr][k0];
        acc2[m][0] = mfma16(a, wb2a[kk], acc2[m][0]);
        acc2[m][1] = mfma16(a, wb2b[kk], acc2[m][1]);
      }
    }
#pragma unroll
    for (int m = 0; m < 4; ++m)
#pragma unroll
      for (int r2 = 0; r2 < 4; ++r2) {
        int row = m * 16 + lg * 4 + r2;
        long node = base + row;
        float h0 = 0.f, h1 = 0.f;
        if (node < NNODES) { h0 = h[node * 128 + c0]; h1 = h[node * 128 + c1]; }
        Xf[row][c0] = acc2[m][0][r2] + bias2_0 + h0;
        Xf[row][c1] = acc2[m][1][r2] + bias2_1 + h1;
      }
    __syncthreads();
    {
      int r = tid >> 2, q = tid & 3;
      float sum = 0.f, ss = 0.f;
      float4 vals[8];
#pragma unroll
      for (int j = 0; j < 8; ++j) {
        float4 v = *(const float4*)&Xf[r][q * 32 + j * 4];
        vals[j] = v;
        sum += v.x + v.y + v.z + v.w;
        ss += v.x * v.x + v.y * v.y + v.z * v.z + v.w * v.w;
      }
      sum += __shfl_xor(sum, 1); sum += __shfl_xor(sum, 2);
      ss  += __shfl_xor(ss, 1);  ss  += __shfl_xor(ss, 2);
      float mean = sum * (1.f / 128.f);
      float var = ss * (1.f / 128.f) - mean * mean;
      float rstd = rsqrtf(var + 1e-5f);
      long node = base + r;
      if (node < NNODES) {
#pragma unroll
        for (int j = 0; j < 8; ++j) {
          int cc = q * 32 + j * 4;
          float4 v = vals[j];
          float4 o;
          o.x = (v.x - mean) * rstd * lng[cc + 0] + lnb[cc + 0];
          o.y = (v.y - mean) * rstd * lng[cc + 1] + lnb[cc + 1];
          o.z = (v.z - mean) * rstd * lng[cc + 2] + lnb[cc + 2];
          o.w = (v.w - mean) * rstd * lng[cc + 3] + lnb[cc + 3];
          *(float4*)(out + node * 128 + cc) = o;
        }
      }
    }
    __syncthreads();
  }
}

extern "C" void kernel_launch(void* const* d_in, const int* in_sizes, int n_in,
                              void* d_out, int out_size, void* d_ws, size_t ws_size,
                              hipStream_t stream) {
  const float* h    = (const float*)d_in[0];
  const int*   ei   = (const int*)d_in[1];
  const float* ex   = (const float*)d_in[2];
  const float* epw1 = (const float*)d_in[3];
  const float* epb1 = (const float*)d_in[4];
  const float* epw2 = (const float*)d_in[5];
  const float* epb2 = (const float*)d_in[6];
  const float* upw1 = (const float*)d_in[7];
  const float* upb1 = (const float*)d_in[8];
  const float* upw2 = (const float*)d_in[9];
  const float* upb2 = (const float*)d_in[10];
  const float* lng  = (const float*)d_in[11];
  const float* lnb  = (const float*)d_in[12];
  float* out = (float*)d_out;
  char* ws = (char*)d_ws;

  const size_t NEED = 444300000ULL;
  if (ws_size >= NEED) {
    unsigned* msg_s = (unsigned*)(ws);                      // 204,800,000
    unsigned* msg_d = (unsigned*)(ws + 204800000);          // 204,800,000
    short* hb    = (short*)(ws + 409600000);                //  25,600,000
    short* w1et  = (short*)(ws + 435200000);
    short* w2et  = (short*)(ws + 435298304);
    short* w1ut  = (short*)(ws + 435331072);
    short* w2ut  = (short*)(ws + 435429376);
    int* cnt_d   = (int*)(ws + 435462144);
    int* cnt_s   = (int*)(ws + 435862144);
    int* off_d   = (int*)(ws + 436262144);
    int* off_s   = (int*)(ws + 436662148);
    int* cur_d   = (int*)(ws + 437062152);
    int* cur_s   = (int*)(ws + 437462152);
    int* slot_s  = (int*)(ws + 437862152);
    int* slot_d  = (int*)(ws + 441062152);
    int* bsum    = (int*)(ws + 444262152);

    hipMemsetAsync(cnt_d, 0, 800000, stream);               // cnt_d + cnt_s
    hipLaunchKernelGGL(k_prep_h, dim3(2048), dim3(256), 0, stream,
                       (const float4*)h, (short4*)hb, NNODES * 128 / 4);
    hipLaunchKernelGGL(k_prep_w, dim3(256), dim3(256), 0, stream,
                       epw1, epw2, upw1, upw2, w1et, w2et, w1ut, w2ut);
    hipLaunchKernelGGL(k_hist, dim3((NEDGES + 255) / 256), dim3(256), 0, stream,
                       ei, cnt_s, cnt_d);
    hipLaunchKernelGGL(k_bsum, dim3(2 * NSEG), dim3(256), 0, stream,
                       cnt_d, cnt_s, bsum);
    hipLaunchKernelGGL(k_soff, dim3(1), dim3(64), 0, stream, bsum, off_d, off_s);
    hipLaunchKernelGGL(k_sfin, dim3(2 * NSEG), dim3(256), 0, stream,
                       cnt_d, cnt_s, bsum, off_d, off_s, cur_d, cur_s);
    hipLaunchKernelGGL(k_scat2, dim3((NEDGES + 255) / 256), dim3(256), 0, stream,
                       ei, cur_s, cur_d, slot_s, slot_d);
    hipLaunchKernelGGL(k_edge2, dim3(768), dim3(256), 0, stream,
                       hb, ei, ex, w1et, w2et, epb1, epb2, slot_s, slot_d,
                       msg_s, msg_d);
    hipLaunchKernelGGL(k_node2, dim3(512), dim3(256), 0, stream,
                       h, hb, msg_d, off_d, msg_s, off_s,
                       w1ut, w2ut, upb1, upb2, lng, lnb, out);
  } else {
    unsigned short* incb  = (unsigned short*)(ws);
    unsigned short* outgb = (unsigned short*)(ws + 25600000);
    float* indeg  = (float*)(ws + 51200000);
    float* outdeg = (float*)(ws + 51600000);
    short* hb     = (short*)(ws + 52000000);
    short* w1et   = (short*)(ws + 77600000);
    short* w2et   = (short*)(ws + 77698304);
    short* w1ut   = (short*)(ws + 77731072);
    short* w2ut   = (short*)(ws + 77829376);

    hipMemsetAsync(ws, 0, 52000000, stream);
    hipLaunchKernelGGL(k_prep_h, dim3(2048), dim3(256), 0, stream,
                       (const float4*)h, (short4*)hb, NNODES * 128 / 4);
    hipLaunchKernelGGL(k_prep_w, dim3(256), dim3(256), 0, stream,
                       epw1, epw2, upw1, upw2, w1et, w2et, w1ut, w2ut);
    hipLaunchKernelGGL(k_edge_at, dim3(1024), dim3(256), 0, stream,
                       hb, ei, ex, w1et, w2et, epb1, epb2, incb, outgb, indeg, outdeg);
    hipLaunchKernelGGL(k_node_at, dim3(512), dim3(256), 0, stream,
                       h, hb, incb, outgb, indeg, outdeg, w1ut, w2ut, upb1, upb2,
                       lng, lnb, out);
  }
}

// Round 11
// 730.308 us; speedup vs baseline: 1.1413x; 1.0281x over previous
//
#include <hip/hip_runtime.h>
#include <stdint.h>

#define HIDD 128
#define NNODES 100000
#define NEDGES 800000
#define NSEG 196          // ceil(100000/512) segments for the scan

typedef short s16x8 __attribute__((ext_vector_type(8)));
typedef float f32x4 __attribute__((ext_vector_type(4)));

__device__ __forceinline__ short f2bf(float f) {
  union { float f; unsigned u; } v; v.f = f;
  return (short)((v.u + 0x7fffu + ((v.u >> 16) & 1u)) >> 16);
}
__device__ __forceinline__ short4 cvt4(float4 v) {
  short4 s; s.x = f2bf(v.x); s.y = f2bf(v.y); s.z = f2bf(v.z); s.w = f2bf(v.w);
  return s;
}
__device__ __forceinline__ float bflo(unsigned w) {
  union { unsigned u; float f; } v; v.u = w << 16; return v.f;
}
__device__ __forceinline__ float bfhi(unsigned w) {
  union { unsigned u; float f; } v; v.u = w & 0xffff0000u; return v.f;
}
__device__ __forceinline__ unsigned pack2(float a, float b) {
  return ((unsigned)(unsigned short)f2bf(b) << 16) | (unsigned)(unsigned short)f2bf(a);
}
__device__ __forceinline__ f32x4 mfma16(s16x8 a, s16x8 b, f32x4 c) {
  return __builtin_amdgcn_mfma_f32_16x16x32_bf16(a, b, c, 0, 0, 0);
}
__device__ __forceinline__ void atomic_pk_bf16(unsigned short* addr, unsigned pk) {
  asm volatile("global_atomic_pk_add_bf16 %0, %1, off" :: "v"(addr), "v"(pk) : "memory");
}

// ---------- prep: h -> bf16 ----------
__global__ void k_prep_h(const float4* __restrict__ h4, short4* __restrict__ hb4, int n4) {
  int stride = gridDim.x * blockDim.x;
  for (int i = blockIdx.x * blockDim.x + threadIdx.x; i < n4; i += stride)
    hb4[i] = cvt4(h4[i]);
}

// ---------- prep: weights -> bf16 [out][in]; w2e col-permuted ----------
__global__ void k_prep_w(const float* __restrict__ w1e, const float* __restrict__ w2e,
                         const float* __restrict__ w1u, const float* __restrict__ w2u,
                         short* __restrict__ w1et, short* __restrict__ w2et,
                         short* __restrict__ w1ut, short* __restrict__ w2ut) {
  int i = blockIdx.x * 256 + threadIdx.x;
  if (i < 49152) {               // dest [128][384]: n=i/384, k=i%384
    int n = i / 384, k = i - n * 384;
    w1et[i] = f2bf(w1e[k * 128 + n]);
    w1ut[i] = f2bf(w1u[k * 128 + n]);
  } else {
    int j = i - 49152;
    if (j < 16384) {             // dest [128][128]: n=j>>7, k=j&127
      int n = j >> 7, k = j & 127;
      int oc = (n & ~31) + 2 * (n & 15) + ((n >> 4) & 1);
      w2et[j] = f2bf(w2e[k * 128 + oc]);   // permuted: lane frag pair = natural cols
      w2ut[j] = f2bf(w2u[k * 128 + n]);    // natural
    }
  }
}

// ================= counting-sort chain (dst direction only) =================
__global__ void k_hist(const int* __restrict__ eidx, int* __restrict__ cnt_s,
                       int* __restrict__ cnt_d) {
  int i = blockIdx.x * 256 + threadIdx.x;
  if (i < NEDGES) {
    atomicAdd(&cnt_s[eidx[i]], 1);             // cnt_s = out-degree (for norm)
    atomicAdd(&cnt_d[eidx[NEDGES + i]], 1);    // cnt_d -> CSR
  }
}

__global__ void k_bsum_d(const int* __restrict__ cnt_d, int* __restrict__ bsum) {
  __shared__ int red[256];
  int b = blockIdx.x, t = threadIdx.x;
  int i0 = b * 512 + 2 * t;
  int a = (i0 < NNODES) ? cnt_d[i0] : 0;
  int c = (i0 + 1 < NNODES) ? cnt_d[i0 + 1] : 0;
  red[t] = a + c;
  __syncthreads();
  for (int d = 128; d > 0; d >>= 1) {
    if (t < d) red[t] += red[t + d];
    __syncthreads();
  }
  if (t == 0) bsum[b] = red[0];
}

__global__ void k_soff_d(int* __restrict__ bsum, int* __restrict__ off_d) {
  if (threadIdx.x == 0) {
    int tot = 0;
    for (int i = 0; i < NSEG; ++i) { int v = bsum[i]; bsum[i] = tot; tot += v; }
    off_d[NNODES] = tot;   // == NEDGES
  }
}

__global__ void k_sfin_d(const int* __restrict__ cnt_d, const int* __restrict__ bsum,
                         int* __restrict__ off_d, int* __restrict__ cur_d) {
  __shared__ int p[256];
  int b = blockIdx.x, t = threadIdx.x;
  int i0 = b * 512 + 2 * t;
  int a = (i0 < NNODES) ? cnt_d[i0] : 0;
  int c = (i0 + 1 < NNODES) ? cnt_d[i0 + 1] : 0;
  p[t] = a + c;
  __syncthreads();
  for (int d = 1; d < 256; d <<= 1) {
    int v = (t >= d) ? p[t - d] : 0;
    __syncthreads();
    p[t] += v;
    __syncthreads();
  }
  int excl = (t ? p[t - 1] : 0) + bsum[b];
  if (i0 < NNODES)     { off_d[i0] = excl;     cur_d[i0] = excl; }
  if (i0 + 1 < NNODES) { off_d[i0 + 1] = excl + a; cur_d[i0 + 1] = excl + a; }
}

__global__ void k_scat_d(const int* __restrict__ eidx, int* __restrict__ cur_d,
                         int* __restrict__ dlist) {
  int i = blockIdx.x * 256 + threadIdx.x;
  if (i < NEDGES) dlist[atomicAdd(&cur_d[eidx[NEDGES + i]], 1)] = i;
}

// ================= edge MLP in dst-sorted order =================
// msg_d written SEQUENTIALLY (zero scatter); src direction via proven pk-bf16
// atomics (half of R3's atomic count). h[dst] gathers are L2-local because
// adjacent tiles share dst nodes.
__global__ __launch_bounds__(256, 2)
void k_edge3(const short* __restrict__ hb, const int* __restrict__ eidx,
             const float* __restrict__ ex,
             const short* __restrict__ w1t, const short* __restrict__ w2t,
             const float* __restrict__ b1g, const float* __restrict__ b2g,
             const int* __restrict__ dlist,
             unsigned* __restrict__ msg_d, unsigned short* __restrict__ outgb) {
  __shared__ __align__(16) short Xs[64][392];   // [h[src]|h[dst]|edge_x], 50176 B
  __shared__ __align__(16) short Hs[64][136];   // hidden, 17408 B
  __shared__ int Es[64], Ss[64];                // edge ids, src ids

  const int tid = threadIdx.x;
  const int wave = tid >> 6, lane = tid & 63;
  const int lg = lane >> 4, lr = lane & 15;
  const int koff = lg * 8;
  const int c0 = wave * 32 + lr, c1 = c0 + 16;
  const int pc0 = wave * 32 + 2 * lr;   // natural col of frag0 (permuted W2)

  s16x8 wb1a[12], wb1b[12], wb2a[4], wb2b[4];
#pragma unroll
  for (int kk = 0; kk < 12; ++kk) {
    wb1a[kk] = *(const s16x8*)(w1t + c0 * 384 + kk * 32 + koff);
    wb1b[kk] = *(const s16x8*)(w1t + c1 * 384 + kk * 32 + koff);
  }
#pragma unroll
  for (int kk = 0; kk < 4; ++kk) {
    wb2a[kk] = *(const s16x8*)(w2t + c0 * 128 + kk * 32 + koff);
    wb2b[kk] = *(const s16x8*)(w2t + c1 * 128 + kk * 32 + koff);
  }
  const float bias1_0 = b1g[c0], bias1_1 = b1g[c1];
  const float bias2_0 = b2g[pc0], bias2_1 = b2g[pc0 + 1];

  for (int t = blockIdx.x; t < NEDGES / 64; t += gridDim.x) {
    const int base = t * 64;

    int myeid = 0;
    if (tid < 64) { myeid = dlist[base + tid]; Es[tid] = myeid; }
    __syncthreads();   // barA: Es ready (also drains prev tile's stores/atomics)

    // Phase A: stage through LDS once per block (R4/R5 lesson)
    for (int u = tid; u < 64 * 32; u += 256) {
      int r = u >> 5, c = u & 31;
      int eid = Es[r];
      int node = (c < 16) ? eidx[eid] : eidx[NEDGES + eid];
      *(int4*)&Xs[r][c * 8] = *(const int4*)(hb + (long)node * 128 + (c & 15) * 8);
    }
    for (int u = tid; u < 64 * 32; u += 256) {
      int r = u >> 5, q = u & 31;
      float4 v = *(const float4*)(ex + (long)Es[r] * 128 + q * 4);
      *(short4*)&Xs[r][256 + q * 4] = cvt4(v);
    }
    if (tid < 64) Ss[tid] = eidx[myeid];
    __syncthreads();   // barB: staging + Ss visible

    // Phase B: layer 1 + relu -> Hs
    f32x4 acc[4][2] = {};
#pragma unroll
    for (int kk = 0; kk < 12; ++kk) {
      int k0 = kk * 32 + koff;
#pragma unroll
      for (int m = 0; m < 4; ++m) {
        s16x8 a = *(const s16x8*)&Xs[m * 16 + lr][k0];
        acc[m][0] = mfma16(a, wb1a[kk], acc[m][0]);
        acc[m][1] = mfma16(a, wb1b[kk], acc[m][1]);
      }
    }
#pragma unroll
    for (int m = 0; m < 4; ++m)
#pragma unroll
      for (int r2 = 0; r2 < 4; ++r2) {
        int row = m * 16 + lg * 4 + r2;
        Hs[row][c0] = f2bf(fmaxf(acc[m][0][r2] + bias1_0, 0.f));
        Hs[row][c1] = f2bf(fmaxf(acc[m][1][r2] + bias1_1, 0.f));
      }
    __syncthreads();   // barC: Hs ready; Xs reads retired

    // Phase C: layer 2 + sequential msg_d store + src pk-atomic
    f32x4 acc2[4][2] = {};
#pragma unroll
    for (int kk = 0; kk < 4; ++kk) {
      int k0 = kk * 32 + koff;
#pragma unroll
      for (int m = 0; m < 4; ++m) {
        s16x8 a = *(const s16x8*)&Hs[m * 16 + lr][k0];
        acc2[m][0] = mfma16(a, wb2a[kk], acc2[m][0]);
        acc2[m][1] = mfma16(a, wb2b[kk], acc2[m][1]);
      }
    }
#pragma unroll
    for (int m = 0; m < 4; ++m)
#pragma unroll
      for (int r2 = 0; r2 < 4; ++r2) {
        int row = m * 16 + lg * 4 + r2;
        unsigned pk = pack2(acc2[m][0][r2] + bias2_0, acc2[m][1][r2] + bias2_1);
        msg_d[(long)(base + row) * 64 + wave * 16 + lr] = pk;   // sequential
        atomic_pk_bf16(outgb + (long)Ss[row] * 128 + pc0, pk);  // src scatter
      }
    // next tile's barA drains these before Es/Ss are overwritten
  }
}

// ================= node: stream dst-CSR msg + outgb read + MLP + LN =================
__global__ __launch_bounds__(256, 2)
void k_node3(const float* __restrict__ h, const short* __restrict__ hb,
             const unsigned* __restrict__ msg_d, const int* __restrict__ off_d,
             const unsigned short* __restrict__ outgb, const int* __restrict__ cnt_s,
             const short* __restrict__ w1t, const short* __restrict__ w2t,
             const float* __restrict__ b1g, const float* __restrict__ b2g,
             const float* __restrict__ lng, const float* __restrict__ lnb,
             float* __restrict__ out) {
  __shared__ __align__(16) char smem[67584];
  short (*Xs)[392] = (short (*)[392])smem;            // 50176 B
  float (*Xf)[132] = (float (*)[132])smem;            // overlay
  short (*Hs)[136] = (short (*)[136])(smem + 50176);  // 17408 B

  const int tid = threadIdx.x;
  const int wave = tid >> 6, lane = tid & 63;
  const int lg = lane >> 4, lr = lane & 15;
  const int koff = lg * 8;
  const int c0 = wave * 32 + lr, c1 = c0 + 16;

  s16x8 wb1a[12], wb1b[12], wb2a[4], wb2b[4];
#pragma unroll
  for (int kk = 0; kk < 12; ++kk) {
    wb1a[kk] = *(const s16x8*)(w1t + c0 * 384 + kk * 32 + koff);
    wb1b[kk] = *(const s16x8*)(w1t + c1 * 384 + kk * 32 + koff);
  }
#pragma unroll
  for (int kk = 0; kk < 4; ++kk) {
    wb2a[kk] = *(const s16x8*)(w2t + c0 * 128 + kk * 32 + koff);
    wb2b[kk] = *(const s16x8*)(w2t + c1 * 128 + kk * 32 + koff);
  }
  const float bias1_0 = b1g[c0], bias1_1 = b1g[c1];
  const float bias2_0 = b2g[c0], bias2_1 = b2g[c1];

#define ACCUM(u0,u1,u2,u3) \
  av[0]+=bflo(u0.x); av[1]+=bfhi(u0.x); av[2]+=bflo(u0.y); av[3]+=bfhi(u0.y); \
  av[4]+=bflo(u0.z); av[5]+=bfhi(u0.z); av[6]+=bflo(u0.w); av[7]+=bfhi(u0.w); \
  av[8]+=bflo(u1.x); av[9]+=bfhi(u1.x); av[10]+=bflo(u1.y); av[11]+=bfhi(u1.y); \
  av[12]+=bflo(u1.z); av[13]+=bfhi(u1.z); av[14]+=bflo(u1.w); av[15]+=bfhi(u1.w); \
  av[16]+=bflo(u2.x); av[17]+=bfhi(u2.x); av[18]+=bflo(u2.y); av[19]+=bfhi(u2.y); \
  av[20]+=bflo(u2.z); av[21]+=bfhi(u2.z); av[22]+=bflo(u2.w); av[23]+=bfhi(u2.w); \
  av[24]+=bflo(u3.x); av[25]+=bfhi(u3.x); av[26]+=bflo(u3.y); av[27]+=bfhi(u3.y); \
  av[28]+=bflo(u3.z); av[29]+=bfhi(u3.z); av[30]+=bflo(u3.w); av[31]+=bfhi(u3.w);

  const int ntiles = (NNODES + 63) / 64;
  for (int t = blockIdx.x; t < ntiles; t += gridDim.x) {
    const int base = t * 64;

    // hb copy [0..127]
    for (int u = tid; u < 64 * 16; u += 256) {
      int r = u >> 4, c = u & 15;
      long node = min(base + r, NNODES - 1);
      *(int4*)&Xs[r][c * 8] = *(const int4*)(hb + node * 128 + c * 8);
    }
    // outgoing = outgb / outdeg -> [256..383]
    for (int u = tid; u < 64 * 16; u += 256) {
      int r = u >> 4, c = u & 15;
      long node = min(base + r, NNODES - 1);
      float s = 1.f / fmaxf((float)cnt_s[node], 1.f);
      uint4 w = *(const uint4*)(outgb + node * 128 + c * 8);
      *(uint4*)&Xs[r][256 + c * 8] = make_uint4(
        pack2(bflo(w.x) * s, bfhi(w.x) * s), pack2(bflo(w.y) * s, bfhi(w.y) * s),
        pack2(bflo(w.z) * s, bfhi(w.z) * s), pack2(bflo(w.w) * s, bfhi(w.w) * s));
    }
    // incoming: stream msg_d rows off_d[n]..off_d[n+1], 2-way unrolled -> [128..255]
    {
      int r = tid >> 2, q = tid & 3;
      long node = base + r;
      bool valid = node < NNODES;
      float av[32];
#pragma unroll
      for (int j = 0; j < 32; ++j) av[j] = 0.f;
      int e0 = 0, e1 = 0;
      if (valid) { e0 = off_d[node]; e1 = off_d[node + 1]; }
      int e = e0;
      for (; e + 1 < e1; e += 2) {
        const uint4* mp0 = (const uint4*)(msg_d + (long)e * 64 + q * 16);
        const uint4* mp1 = (const uint4*)(msg_d + (long)(e + 1) * 64 + q * 16);
        uint4 a0 = mp0[0], a1 = mp0[1], a2 = mp0[2], a3 = mp0[3];
        uint4 b0 = mp1[0], b1 = mp1[1], b2 = mp1[2], b3 = mp1[3];
        ACCUM(a0, a1, a2, a3)
        ACCUM(b0, b1, b2, b3)
      }
      if (e < e1) {
        const uint4* mp0 = (const uint4*)(msg_d + (long)e * 64 + q * 16);
        uint4 a0 = mp0[0], a1 = mp0[1], a2 = mp0[2], a3 = mp0[3];
        ACCUM(a0, a1, a2, a3)
      }
      float sc = 1.f / fmaxf((float)(e1 - e0), 1.f);
      unsigned pk[16];
#pragma unroll
      for (int j = 0; j < 16; ++j) pk[j] = pack2(av[2 * j] * sc, av[2 * j + 1] * sc);
      uint4* dst = (uint4*)&Xs[r][128 + q * 32];
      dst[0] = make_uint4(pk[0], pk[1], pk[2], pk[3]);
      dst[1] = make_uint4(pk[4], pk[5], pk[6], pk[7]);
      dst[2] = make_uint4(pk[8], pk[9], pk[10], pk[11]);
      dst[3] = make_uint4(pk[12], pk[13], pk[14], pk[15]);
    }
    __syncthreads();

    // MLP layer 1
    f32x4 acc[4][2] = {};
#pragma unroll
    for (int kk = 0; kk < 12; ++kk) {
      int k0 = kk * 32 + koff;
#pragma unroll
      for (int m = 0; m < 4; ++m) {
        s16x8 a = *(const s16x8*)&Xs[m * 16 + lr][k0];
        acc[m][0] = mfma16(a, wb1a[kk], acc[m][0]);
        acc[m][1] = mfma16(a, wb1b[kk], acc[m][1]);
      }
    }
#pragma unroll
    for (int m = 0; m < 4; ++m)
#pragma unroll
      for (int r2 = 0; r2 < 4; ++r2) {
        int row = m * 16 + lg * 4 + r2;
        Hs[row][c0] = f2bf(fmaxf(acc[m][0][r2] + bias1_0, 0.f));
        Hs[row][c1] = f2bf(fmaxf(acc[m][1][r2] + bias1_1, 0.f));
      }
    __syncthreads();

    // MLP layer 2 + residual -> Xf
    f32x4 acc2[4][2] = {};
#pragma unroll
    for (int kk = 0; kk < 4; ++kk) {
      int k0 = kk * 32 + koff;
#pragma unroll
      for (int m = 0; m < 4; ++m) {
        s16x8 a = *(const s16x8*)&Hs[m * 16 + lr][k0];
        acc2[m][0] = mfma16(a, wb2a[kk], acc2[m][0]);
        acc2[m][1] = mfma16(a, wb2b[kk], acc2[m][1]);
      }
    }
#pragma unroll
    for (int m = 0; m < 4; ++m)
#pragma unroll
      for (int r2 = 0; r2 < 4; ++r2) {
        int row = m * 16 + lg * 4 + r2;
        long node = base + row;
        float h0 = 0.f, h1 = 0.f;
        if (node < NNODES) { h0 = h[node * 128 + c0]; h1 = h[node * 128 + c1]; }
        Xf[row][c0] = acc2[m][0][r2] + bias2_0 + h0;
        Xf[row][c1] = acc2[m][1][r2] + bias2_1 + h1;
      }
    __syncthreads();

    // LayerNorm + store
    {
      int r = tid >> 2, q = tid & 3;
      float sum = 0.f, ss = 0.f;
      float4 vals[8];
#pragma unroll
      for (int j = 0; j < 8; ++j) {
        float4 v = *(const float4*)&Xf[r][q * 32 + j * 4];
        vals[j] = v;
        sum += v.x + v.y + v.z + v.w;
        ss += v.x * v.x + v.y * v.y + v.z * v.z + v.w * v.w;
      }
      sum += __shfl_xor(sum, 1); sum += __shfl_xor(sum, 2);
      ss  += __shfl_xor(ss, 1);  ss  += __shfl_xor(ss, 2);
      float mean = sum * (1.f / 128.f);
      float var = ss * (1.f / 128.f) - mean * mean;
      float rstd = rsqrtf(var + 1e-5f);
      long node = base + r;
      if (node < NNODES) {
#pragma unroll
        for (int j = 0; j < 8; ++j) {
          int cc = q * 32 + j * 4;
          float4 v = vals[j];
          float4 o;
          o.x = (v.x - mean) * rstd * lng[cc + 0] + lnb[cc + 0];
          o.y = (v.y - mean) * rstd * lng[cc + 1] + lnb[cc + 1];
          o.z = (v.z - mean) * rstd * lng[cc + 2] + lnb[cc + 2];
          o.w = (v.w - mean) * rstd * lng[cc + 3] + lnb[cc + 3];
          *(float4*)(out + node * 128 + cc) = o;
        }
      }
    }
    __syncthreads();
  }
#undef ACCUM
}

// ================= fallback path (R3, proven): pk-bf16 atomics both dirs =================
__global__ __launch_bounds__(256, 2)
void k_edge_at(const short* __restrict__ hb, const int* __restrict__ eidx,
               const float* __restrict__ ex,
               const short* __restrict__ w1t, const short* __restrict__ w2t,
               const float* __restrict__ b1g, const float* __restrict__ b2g,
               unsigned short* __restrict__ incb, unsigned short* __restrict__ outgb,
               float* __restrict__ indeg, float* __restrict__ outdeg) {
  __shared__ __align__(16) short Xs[64][392];
  __shared__ __align__(16) short Hs[64][136];
  const int tid = threadIdx.x;
  const int wave = tid >> 6, lane = tid & 63;
  const int lg = lane >> 4, lr = lane & 15;
  const int koff = lg * 8;
  const int c0 = wave * 32 + lr, c1 = c0 + 16;
  const int pc0 = wave * 32 + 2 * lr;
  s16x8 wb1a[12], wb1b[12], wb2a[4], wb2b[4];
#pragma unroll
  for (int kk = 0; kk < 12; ++kk) {
    wb1a[kk] = *(const s16x8*)(w1t + c0 * 384 + kk * 32 + koff);
    wb1b[kk] = *(const s16x8*)(w1t + c1 * 384 + kk * 32 + koff);
  }
#pragma unroll
  for (int kk = 0; kk < 4; ++kk) {
    wb2a[kk] = *(const s16x8*)(w2t + c0 * 128 + kk * 32 + koff);
    wb2b[kk] = *(const s16x8*)(w2t + c1 * 128 + kk * 32 + koff);
  }
  const float bias1_0 = b1g[c0], bias1_1 = b1g[c1];
  const float bias2_0 = b2g[pc0], bias2_1 = b2g[pc0 + 1];
  for (int t = blockIdx.x; t < NEDGES / 64; t += gridDim.x) {
    const int base = t * 64;
    for (int u = tid; u < 64 * 32; u += 256) {
      int r = u >> 5, c = u & 31;
      int node = (c < 16) ? eidx[base + r] : eidx[NEDGES + base + r];
      *(int4*)&Xs[r][c * 8] = *(const int4*)(hb + (long)node * 128 + (c & 15) * 8);
    }
    for (int u = tid; u < 64 * 32; u += 256) {
      int r = u >> 5, q = u & 31;
      float4 v = *(const float4*)(ex + (long)(base + r) * 128 + q * 4);
      *(short4*)&Xs[r][256 + q * 4] = cvt4(v);
    }
    if (tid < 64) {
      atomicAdd(&outdeg[eidx[base + tid]], 1.0f);
      atomicAdd(&indeg[eidx[NEDGES + base + tid]], 1.0f);
    }
    __syncthreads();
    f32x4 acc[4][2] = {};
#pragma unroll
    for (int kk = 0; kk < 12; ++kk) {
      int k0 = kk * 32 + koff;
#pragma unroll
      for (int m = 0; m < 4; ++m) {
        s16x8 a = *(const s16x8*)&Xs[m * 16 + lr][k0];
        acc[m][0] = mfma16(a, wb1a[kk], acc[m][0]);
        acc[m][1] = mfma16(a, wb1b[kk], acc[m][1]);
      }
    }
#pragma unroll
    for (int m = 0; m < 4; ++m)
#pragma unroll
      for (int r2 = 0; r2 < 4; ++r2) {
        int row = m * 16 + lg * 4 + r2;
        Hs[row][c0] = f2bf(fmaxf(acc[m][0][r2] + bias1_0, 0.f));
        Hs[row][c1] = f2bf(fmaxf(acc[m][1][r2] + bias1_1, 0.f));
      }
    __syncthreads();
    f32x4 acc2[4][2] = {};
#pragma unroll
    for (int kk = 0; kk < 4; ++kk) {
#pragma unroll
      for (int m = 0; m < 4; ++m) {
        s16x8 a = *(const s16x8*)&Hs[m * 16 + lr][kk * 32 + koff];
        acc2[m][0] = mfma16(a, wb2a[kk], acc2[m][0]);
        acc2[m][1] = mfma16(a, wb2b[kk], acc2[m][1]);
      }
    }
#pragma unroll
    for (int m = 0; m < 4; ++m)
#pragma unroll
      for (int r2 = 0; r2 < 4; ++r2) {
        int row = m * 16 + lg * 4 + r2;
        int s = eidx[base + row], d = eidx[NEDGES + base + row];
        unsigned pk = pack2(acc2[m][0][r2] + bias2_0, acc2[m][1][r2] + bias2_1);
        atomic_pk_bf16(outgb + (long)s * 128 + pc0, pk);
        atomic_pk_bf16(incb + (long)d * 128 + pc0, pk);
      }
  }
}

__global__ __launch_bounds__(256, 2)
void k_node_at(const float* __restrict__ h, const short* __restrict__ hb,
               const unsigned short* __restrict__ incb,
               const unsigned short* __restrict__ outgb,
               const float* __restrict__ indeg, const float* __restrict__ outdeg,
               const short* __restrict__ w1t, const short* __restrict__ w2t,
               const float* __restrict__ b1g, const float* __restrict__ b2g,
               const float* __restrict__ lng, const float* __restrict__ lnb,
               float* __restrict__ out) {
  __shared__ __align__(16) char smem[67584];
  short (*Xs)[392] = (short (*)[392])smem;
  float (*Xf)[132] = (float (*)[132])smem;
  short (*Hs)[136] = (short (*)[136])(smem + 50176);
  const int tid = threadIdx.x;
  const int wave = tid >> 6, lane = tid & 63;
  const int lg = lane >> 4, lr = lane & 15;
  const int koff = lg * 8;
  const int c0 = wave * 32 + lr, c1 = c0 + 16;
  s16x8 wb1a[12], wb1b[12], wb2a[4], wb2b[4];
#pragma unroll
  for (int kk = 0; kk < 12; ++kk) {
    wb1a[kk] = *(const s16x8*)(w1t + c0 * 384 + kk * 32 + koff);
    wb1b[kk] = *(const s16x8*)(w1t + c1 * 384 + kk * 32 + koff);
  }
#pragma unroll
  for (int kk = 0; kk < 4; ++kk) {
    wb2a[kk] = *(const s16x8*)(w2t + c0 * 128 + kk * 32 + koff);
    wb2b[kk] = *(const s16x8*)(w2t + c1 * 128 + kk * 32 + koff);
  }
  const float bias1_0 = b1g[c0], bias1_1 = b1g[c1];
  const float bias2_0 = b2g[c0], bias2_1 = b2g[c1];
  const int ntiles = (NNODES + 63) / 64;
  for (int t = blockIdx.x; t < ntiles; t += gridDim.x) {
    const int base = t * 64;
    for (int u = tid; u < 64 * 16; u += 256) {
      int r = u >> 4, c = u & 15;
      long node = min(base + r, NNODES - 1);
      *(int4*)&Xs[r][c * 8] = *(const int4*)(hb + node * 128 + c * 8);
    }
    for (int u = tid; u < 64 * 16; u += 256) {
      int r = u >> 4, c = u & 15;
      long node = min(base + r, NNODES - 1);
      float s = 1.f / fmaxf(indeg[node], 1.f);
      uint4 w = *(const uint4*)(incb + node * 128 + c * 8);
      *(uint4*)&Xs[r][128 + c * 8] = make_uint4(
        pack2(bflo(w.x) * s, bfhi(w.x) * s), pack2(bflo(w.y) * s, bfhi(w.y) * s),
        pack2(bflo(w.z) * s, bfhi(w.z) * s), pack2(bflo(w.w) * s, bfhi(w.w) * s));
    }
    for (int u = tid; u < 64 * 16; u += 256) {
      int r = u >> 4, c = u & 15;
      long node = min(base + r, NNODES - 1);
      float s = 1.f / fmaxf(outdeg[node], 1.f);
      uint4 w = *(const uint4*)(outgb + node * 128 + c * 8);
      *(uint4*)&Xs[r][256 + c * 8] = make_uint4(
        pack2(bflo(w.x) * s, bfhi(w.x) * s), pack2(bflo(w.y) * s, bfhi(w.y) * s),
        pack2(bflo(w.z) * s, bfhi(w.z) * s), pack2(bflo(w.w) * s, bfhi(w.w) * s));
    }
    __syncthreads();
    f32x4 acc[4][2] = {};
#pragma unroll
    for (int kk = 0; kk < 12; ++kk) {
      int k0 = kk * 32 + koff;
#pragma unroll
      for (int m = 0; m < 4; ++m) {
        s16x8 a = *(const s16x8*)&Xs[m * 16 + lr][k0];
        acc[m][0] = mfma16(a, wb1a[kk], acc[m][0]);
        acc[m][1] = mfma16(a, wb1b[kk], acc[m][1]);
      }
    }
#pragma unroll
    for (int m = 0; m < 4; ++m)
#pragma unroll
      for (int r2 = 0; r2 < 4; ++r2) {
        int row = m * 16 + lg * 4 + r2;
        Hs[row][c0] = f2bf(fmaxf(acc[m][0][r2] + bias1_0, 0.f));
        Hs[row][c1] = f2bf(fmaxf(acc[m][1][r2] + bias1_1, 0.f));
      }
    __syncthreads();
    f32x4 acc2[4][2] = {};
#pragma unroll
    for (int kk = 0; kk < 4; ++kk) {
      int k0 = kk * 32 + koff;
#pragma unroll
      for (int m = 0; m < 4; ++m) {
        s16x8 a = *(const s16x8*)&Hs[m * 16 + lr][k0];
        acc2[m][0] = mfma16(a, wb2a[kk], acc2[m][0]);
        acc2[m][1] = mfma16(a, wb2b[kk], acc2[m][1]);
      }
    }
#pragma unroll
    for (int m = 0; m < 4; ++m)
#pragma unroll
      for (int r2 = 0; r2 < 4; ++r2) {
        int row = m * 16 + lg * 4 + r2;
        long node = base + row;
        float h0 = 0.f, h1 = 0.f;
        if (node < NNODES) { h0 = h[node * 128 + c0]; h1 = h[node * 128 + c1]; }
        Xf[row][c0] = acc2[m][0][r2] + bias2_0 + h0;
        Xf[row][c1] = acc2[m][1][r2] + bias2_1 + h1;
      }
    __syncthreads();
    {
      int r = tid >> 2, q = tid & 3;
      float sum = 0.f, ss = 0.f;
      float4 vals[8];
#pragma unroll
      for (int j = 0; j < 8; ++j) {
        float4 v = *(const float4*)&Xf[r][q * 32 + j * 4];
        vals[j] = v;
        sum += v.x + v.y + v.z + v.w;
        ss += v.x * v.x + v.y * v.y + v.z * v.z + v.w * v.w;
      }
      sum += __shfl_xor(sum, 1); sum += __shfl_xor(sum, 2);
      ss  += __shfl_xor(ss, 1);  ss  += __shfl_xor(ss, 2);
      float mean = sum * (1.f / 128.f);
      float var = ss * (1.f / 128.f) - mean * mean;
      float rstd = rsqrtf(var + 1e-5f);
      long node = base + r;
      if (node < NNODES) {
#pragma unroll
        for (int j = 0; j < 8; ++j) {
          int cc = q * 32 + j * 4;
          float4 v = vals[j];
          float4 o;
          o.x = (v.x - mean) * rstd * lng[cc + 0] + lnb[cc + 0];
          o.y = (v.y - mean) * rstd * lng[cc + 1] + lnb[cc + 1];
          o.z = (v.z - mean) * rstd * lng[cc + 2] + lnb[cc + 2];
          o.w = (v.w - mean) * rstd * lng[cc + 3] + lnb[cc + 3];
          *(float4*)(out + node * 128 + cc) = o;
        }
      }
    }
    __syncthreads();
  }
}

extern "C" void kernel_launch(void* const* d_in, const int* in_sizes, int n_in,
                              void* d_out, int out_size, void* d_ws, size_t ws_size,
                              hipStream_t stream) {
  const float* h    = (const float*)d_in[0];
  const int*   ei   = (const int*)d_in[1];
  const float* ex   = (const float*)d_in[2];
  const float* epw1 = (const float*)d_in[3];
  const float* epb1 = (const float*)d_in[4];
  const float* epw2 = (const float*)d_in[5];
  const float* epb2 = (const float*)d_in[6];
  const float* upw1 = (const float*)d_in[7];
  const float* upb1 = (const float*)d_in[8];
  const float* upw2 = (const float*)d_in[9];
  const float* upb2 = (const float*)d_in[10];
  const float* lng  = (const float*)d_in[11];
  const float* lnb  = (const float*)d_in[12];
  float* out = (float*)d_out;
  char* ws = (char*)d_ws;

  const size_t NEED = 261100000ULL;
  if (ws_size >= NEED) {
    // ---------- dst-sorted stream + src-atomic hybrid ----------
    unsigned* msg_d = (unsigned*)(ws);                       // 204,800,000
    unsigned short* outgb = (unsigned short*)(ws + 204800000); // 25,600,000
    short* hb    = (short*)(ws + 230400000);                 //  25,600,000
    short* w1et  = (short*)(ws + 256000000);                 //      98,304
    short* w2et  = (short*)(ws + 256098304);                 //      32,768
    short* w1ut  = (short*)(ws + 256131072);                 //      98,304
    short* w2ut  = (short*)(ws + 256229376);                 //      32,768
    int* cnt_d   = (int*)(ws + 256262144);                   //     400,000
    int* cnt_s   = (int*)(ws + 256662144);                   //     400,000
    int* off_d   = (int*)(ws + 257062144);                   //     400,004
    int* cur_d   = (int*)(ws + 257462148);                   //     400,000
    int* dlist   = (int*)(ws + 257862148);                   //   3,200,000
    int* bsum    = (int*)(ws + 261062148);                   //         784

    hipMemsetAsync(outgb, 0, 25600000, stream);
    hipMemsetAsync(cnt_d, 0, 800000, stream);                // cnt_d + cnt_s
    hipLaunchKernelGGL(k_prep_h, dim3(2048), dim3(256), 0, stream,
                       (const float4*)h, (short4*)hb, NNODES * 128 / 4);
    hipLaunchKernelGGL(k_prep_w, dim3(256), dim3(256), 0, stream,
                       epw1, epw2, upw1, upw2, w1et, w2et, w1ut, w2ut);
    hipLaunchKernelGGL(k_hist, dim3((NEDGES + 255) / 256), dim3(256), 0, stream,
                       ei, cnt_s, cnt_d);
    hipLaunchKernelGGL(k_bsum_d, dim3(NSEG), dim3(256), 0, stream, cnt_d, bsum);
    hipLaunchKernelGGL(k_soff_d, dim3(1), dim3(64), 0, stream, bsum, off_d);
    hipLaunchKernelGGL(k_sfin_d, dim3(NSEG), dim3(256), 0, stream,
                       cnt_d, bsum, off_d, cur_d);
    hipLaunchKernelGGL(k_scat_d, dim3((NEDGES + 255) / 256), dim3(256), 0, stream,
                       ei, cur_d, dlist);
    hipLaunchKernelGGL(k_edge3, dim3(1024), dim3(256), 0, stream,
                       hb, ei, ex, w1et, w2et, epb1, epb2, dlist, msg_d, outgb);
    hipLaunchKernelGGL(k_node3, dim3(512), dim3(256), 0, stream,
                       h, hb, msg_d, off_d, outgb, cnt_s,
                       w1ut, w2ut, upb1, upb2, lng, lnb, out);
  } else {
    // ---------- fallback: proven R3 atomic path ----------
    unsigned short* incb  = (unsigned short*)(ws);             // 25,600,000
    unsigned short* outgb = (unsigned short*)(ws + 25600000);  // 25,600,000
    float* indeg  = (float*)(ws + 51200000);
    float* outdeg = (float*)(ws + 51600000);
    short* hb     = (short*)(ws + 52000000);
    short* w1et   = (short*)(ws + 77600000);
    short* w2et   = (short*)(ws + 77698304);
    short* w1ut   = (short*)(ws + 77731072);
    short* w2ut   = (short*)(ws + 77829376);

    hipMemsetAsync(ws, 0, 52000000, stream);
    hipLaunchKernelGGL(k_prep_h, dim3(2048), dim3(256), 0, stream,
                       (const float4*)h, (short4*)hb, NNODES * 128 / 4);
    hipLaunchKernelGGL(k_prep_w, dim3(256), dim3(256), 0, stream,
                       epw1, epw2, upw1, upw2, w1et, w2et, w1ut, w2ut);
    hipLaunchKernelGGL(k_edge_at, dim3(1024), dim3(256), 0, stream,
                       hb, ei, ex, w1et, w2et, epb1, epb2, incb, outgb, indeg, outdeg);
    hipLaunchKernelGGL(k_node_at, dim3(512), dim3(256), 0, stream,
                       h, hb, incb, outgb, indeg, outdeg, w1ut, w2ut, upb1, upb2,
                       lng, lnb, out);
  }
}